// Round 1
// baseline (1161.108 us; speedup 1.0000x reference)
//
#include <hip/hip_runtime.h>
#include <hip/hip_bf16.h>
#include <hip/hip_fp16.h>
#include <math.h>

#define T_TOK 8192
#define DIM   1024
#define HID   4096
#define NE    8
#define NT256 72                    // max 256-row slabs: 16384 + 8*255 <= 72*256
#define CAP_ROWS (NT256 * 256)      // 18432 padded slots

typedef _Float16 f16x8 __attribute__((ext_vector_type(8)));
typedef float    floatx4 __attribute__((ext_vector_type(4)));

__device__ __forceinline__ void gload_lds16(const void* g, void* l) {
    __builtin_amdgcn_global_load_lds(
        (const __attribute__((address_space(1))) void*)g,
        (__attribute__((address_space(3))) void*)l,
        16, 0, 0);
}

// tanh-form GELU (max dev from exact ~1e-3)
__device__ __forceinline__ float gelu_f(float v) {
    float u = v * (0.7978845608028654f + 0.03567740813636141f * v * v);
    float e = exp2f(2.8853900817779268f * u);     // exp(2u)
    float th = 1.f - 2.f / (e + 1.f);
    return 0.5f * v * (1.f + th);
}

// ---------------- Pass 1a: gating + LN stats ----------------
__global__ __launch_bounds__(256) void gating_ln_kernel(
    const float* __restrict__ x, const float* __restrict__ gw,
    int* __restrict__ sel, float* __restrict__ wts,
    float* __restrict__ mu_arr, float* __restrict__ rstd_arr,
    int* __restrict__ counts)
{
    int t = blockIdx.x;
    int tid = threadIdx.x;
    float4 xv = ((const float4*)(x + (size_t)t * DIM))[tid];
    float s  = xv.x + xv.y + xv.z + xv.w;
    float ss = xv.x*xv.x + xv.y*xv.y + xv.z*xv.z + xv.w*xv.w;
    float l[NE];
#pragma unroll
    for (int e = 0; e < NE; e++) l[e] = 0.f;
    int d0 = tid * 4;
    const float* xp = &xv.x;
#pragma unroll
    for (int j = 0; j < 4; j++) {
        float xj = xp[j];
        const float4* g = (const float4*)(gw + (size_t)(d0 + j) * NE);
        float4 g0 = g[0], g1 = g[1];
        l[0] += xj * g0.x; l[1] += xj * g0.y; l[2] += xj * g0.z; l[3] += xj * g0.w;
        l[4] += xj * g1.x; l[5] += xj * g1.y; l[6] += xj * g1.z; l[7] += xj * g1.w;
    }
#pragma unroll
    for (int off = 32; off > 0; off >>= 1) {
        s  += __shfl_down(s, off);
        ss += __shfl_down(ss, off);
#pragma unroll
        for (int e = 0; e < NE; e++) l[e] += __shfl_down(l[e], off);
    }
    __shared__ float red[4][10];
    int lane = tid & 63, wv = tid >> 6;
    if (lane == 0) {
        red[wv][0] = s; red[wv][1] = ss;
        for (int e = 0; e < NE; e++) red[wv][2 + e] = l[e];
    }
    __syncthreads();
    if (tid == 0) {
        float S = 0.f, SS = 0.f, L[NE];
        for (int e = 0; e < NE; e++) L[e] = 0.f;
        for (int w = 0; w < 4; w++) {
            S += red[w][0]; SS += red[w][1];
            for (int e = 0; e < NE; e++) L[e] += red[w][2 + e];
        }
        float mu  = S * (1.f / DIM);
        float var = SS * (1.f / DIM) - mu * mu;
        float rstd = rsqrtf(var + 1e-5f);
        float lmax = L[0];
        for (int e = 1; e < NE; e++) lmax = fmaxf(lmax, L[e]);
        float den = 0.f;
        for (int e = 0; e < NE; e++) den += expf(L[e] - lmax);
        int i0 = 0; float b0 = L[0];
        for (int e = 1; e < NE; e++) if (L[e] > b0) { b0 = L[e]; i0 = e; }
        int i1 = -1; float b1v = -3.4e38f;
        for (int e = 0; e < NE; e++) if (e != i0 && L[e] > b1v) { b1v = L[e]; i1 = e; }
        float p0 = expf(b0 - lmax) / den;
        float p1 = expf(b1v - lmax) / den;
        float t1 = expf(p1 - p0);            // p1 <= p0, stable
        float w0 = 1.f / (1.f + t1);
        float w1 = t1 / (1.f + t1);
        sel[2*t] = i0;  sel[2*t+1] = i1;
        wts[2*t] = w0;  wts[2*t+1] = w1;
        mu_arr[t] = mu; rstd_arr[t] = rstd;
        atomicAdd(&counts[i0], 1);
        atomicAdd(&counts[i1], 1);
    }
}

// ---------------- Pass 1b: 256-aligned offsets + tile->expert map (parallel) ----------------
__global__ __launch_bounds__(256) void build_offsets_kernel(
    const int* __restrict__ counts, int* __restrict__ off,
    int* __restrict__ cursor, int* __restrict__ tile_expert)
{
    __shared__ int soff[NE + 1];
    int tid = threadIdx.x;
    if (tid == 0) {
        int o = 0;
        for (int e = 0; e < NE; e++) {
            off[e] = soff[e] = o;
            o += ((counts[e] + 255) >> 8) << 8;
            cursor[e] = 0;
        }
        off[NE] = soff[NE] = o;
    }
    __syncthreads();
    int o = soff[NE];
    for (int i = tid; i < NT256; i += 256) {
        int pos = i * 256, e = -1;
        if (pos < o) {
            for (int j = 0; j < NE; j++)
                if (pos >= soff[j] && pos < soff[j + 1]) { e = j; break; }
        }
        tile_expert[i] = e;
    }
}

// ---------------- Pass 1c: scatter normalized tokens (LN affine folded) ----------------
__global__ __launch_bounds__(256) void scatter_kernel(
    const float* __restrict__ x, const float* __restrict__ ln_s, const float* __restrict__ ln_b,
    const int* __restrict__ sel,
    const float* __restrict__ mu_arr, const float* __restrict__ rstd_arr,
    const int* __restrict__ off, int* __restrict__ cursor,
    _Float16* __restrict__ xg, int* __restrict__ slot_of)
{
    int t = blockIdx.x, tid = threadIdx.x;
    __shared__ int sslot[2];
    int e0 = sel[2*t], e1 = sel[2*t+1];
    if (tid == 0) {
        int s0 = off[e0] + atomicAdd(&cursor[e0], 1);
        int s1 = off[e1] + atomicAdd(&cursor[e1], 1);
        sslot[0] = s0; sslot[1] = s1;
        slot_of[2*t] = s0; slot_of[2*t+1] = s1;
    }
    __syncthreads();
    float4 xv = ((const float4*)(x + (size_t)t * DIM))[tid];
    float mu = mu_arr[t], rstd = rstd_arr[t];
    float xn0 = (xv.x - mu) * rstd, xn1 = (xv.y - mu) * rstd;
    float xn2 = (xv.z - mu) * rstd, xn3 = (xv.w - mu) * rstd;
#pragma unroll
    for (int k = 0; k < 2; k++) {
        int e = (k == 0) ? e0 : e1;
        int slot = sslot[k];
        float4 sv = ((const float4*)(ln_s + (size_t)e * DIM))[tid];
        float4 bv = ((const float4*)(ln_b + (size_t)e * DIM))[tid];
        _Float16 hb[4];
        hb[0] = (_Float16)(xn0 * sv.x + bv.x);
        hb[1] = (_Float16)(xn1 * sv.y + bv.y);
        hb[2] = (_Float16)(xn2 * sv.z + bv.z);
        hb[3] = (_Float16)(xn3 * sv.w + bv.w);
        *(uint2*)(xg + (size_t)slot * DIM + tid * 4) = *(const uint2*)hb;
    }
}

// ---------------- Weight transpose + fp32->fp16 convert ----------------
__global__ __launch_bounds__(256) void transpose_cvt_kernel(
    const float* __restrict__ in, _Float16* __restrict__ out, int R, int C)
{
    __shared__ _Float16 tile[64][65];
    size_t ebase = (size_t)blockIdx.z * R * C;
    const float* inp = in + ebase + (size_t)(blockIdx.y * 64) * C + blockIdx.x * 64;
    _Float16* outp = out + ebase + (size_t)(blockIdx.x * 64) * R + blockIdx.y * 64;
    int t = threadIdx.x & 31, j0 = threadIdx.x >> 5;
    for (int j = j0; j < 64; j += 8) {
        float2 v = *(const float2*)(inp + (size_t)j * C + 2 * t);
        tile[j][2*t]   = (_Float16)v.x;
        tile[j][2*t+1] = (_Float16)v.y;
    }
    __syncthreads();
    for (int j = j0; j < 64; j += 8) {
        _Float16 pr[2] = { tile[2*t][j], tile[2*t+1][j] };
        *(unsigned int*)(outp + (size_t)j * R + 2 * t) = *(unsigned int*)pr;
    }
}

// ================= 8-phase 256-row-tile GEMM (T2+T3+T4+T5) =================
// BM=256, BK=64, 512 threads (8 waves, 2 waves/SIMD, 1 block/CU).
// A = [rows][K] fp16 (xg or H1); B = [N][K] fp16 (pre-transposed weights).
// LDS: 2 buffers x (A 32KB + B BN*128B). Halves are wave-interleaved so each
// staged 8KB chunk is exactly the data one phase's ds_reads consume.
// st_16x32 swizzle: linear gload_lds dest, source col ^ ((ldsrow>>2&1)<<5),
// same XOR on ds_read (involution, rule 21).

#define BAR() __builtin_amdgcn_s_barrier()
#define WAITLGKM() asm volatile("s_waitcnt lgkmcnt(0)" ::: "memory")
#define SCB() __builtin_amdgcn_sched_barrier(0)
#define VMC0() asm volatile("s_waitcnt vmcnt(0)" ::: "memory")
#define VMCN() do { if (LPB == 2) { asm volatile("s_waitcnt vmcnt(6)" ::: "memory"); } \
                    else          { asm volatile("s_waitcnt vmcnt(5)" ::: "memory"); } } while (0)

#define DSA(B_, MHI) do {                                                        \
    const char* p_ = smb + (B_) * (2 * BUFH) + (MHI) * 16384 + aob;              \
    _Pragma("unroll")                                                            \
    for (int mi_ = 0; mi_ < MH; ++mi_) {                                         \
        af[mi_][0] = *(const f16x8*)(p_ + mi_ * 2048);                           \
        af[mi_][1] = *(const f16x8*)(p_ + mi_ * 2048 + 64);                      \
    }                                                                            \
} while (0)

#define DSB(B_, NHI) do {                                                        \
    const char* p_ = smb + (B_) * (2 * BUFH) + (NHI) * (BN * 64) + bob;          \
    _Pragma("unroll")                                                            \
    for (int tn_ = 0; tn_ < 2; ++tn_) {                                          \
        bf[tn_][0] = *(const f16x8*)(p_ + tn_ * 2048);                           \
        bf[tn_][1] = *(const f16x8*)(p_ + tn_ * 2048 + 64);                      \
    }                                                                            \
} while (0)

#define STA(B_, KOFF, H_) do {                                                   \
    _Float16* d_ = smem + (B_) * BUFH + (H_) * 8192 + tid * 8;                   \
    gload_lds16(gA0 + (size_t)((H_) * (WM / 2)) * K + (KOFF), d_);               \
    gload_lds16(gA1 + (size_t)((H_) * (WM / 2)) * K + (KOFF), d_ + 4096);        \
} while (0)

#define STB(B_, KOFF, H_) do {                                                   \
    _Float16* d_ = smem + (B_) * BUFH + 16384 + (H_) * BHH + tid * 8;            \
    gload_lds16(gB0 + (size_t)((H_) * 32) * K + (KOFF), d_);                     \
    if (LPB == 2) gload_lds16(gB1 + (size_t)((H_) * 32) * K + (KOFF), d_ + 4096);\
} while (0)

#define MM(MHI, NHI) do {                                                        \
    _Pragma("unroll")                                                            \
    for (int mi_ = 0; mi_ < MH; ++mi_) {                                         \
        _Pragma("unroll")                                                        \
        for (int tn_ = 0; tn_ < 2; ++tn_) {                                      \
            floatx4* a_ = &acc[(MHI) * MH + mi_][(NHI) * 2 + tn_];               \
            *a_ = __builtin_amdgcn_mfma_f32_16x16x32_f16(af[mi_][0], bf[tn_][0], *a_, 0, 0, 0); \
            *a_ = __builtin_amdgcn_mfma_f32_16x16x32_f16(af[mi_][1], bf[tn_][1], *a_, 0, 0, 0); \
        }                                                                        \
    }                                                                            \
} while (0)

#define PH_MM(MHI, NHI)                                                          \
    BAR(); WAITLGKM(); SCB();                                                    \
    __builtin_amdgcn_s_setprio(1); MM(MHI, NHI); __builtin_amdgcn_s_setprio(0);

// stage schedule (iter i, K-tiles 2i/2i+1 live, staging 2i+2/2i+3):
// ph1:B1h0(kt2i+1) ph2:A0h0 ph3:B0h1 ph4:A0h1 [vmcnt] ph5:B0h0 ph6:A1h0 ph7:B1h1 ph8:A1h1 [vmcnt]
#define ITER(SON) do {                                                           \
    DSA(0, 0); DSB(0, 0); STB(1, 64, 0);                                         \
    PH_MM(0, 0) BAR();                                                           \
    DSB(0, 1); if (SON) STA(0, 128, 0);                                          \
    PH_MM(0, 1) BAR();                                                           \
    DSA(0, 1); if (SON) STB(0, 128, 1);                                          \
    PH_MM(1, 1) BAR();                                                           \
    DSB(0, 0); if (SON) STA(0, 128, 1);                                          \
    PH_MM(1, 0) if (SON) { VMCN(); } else { VMC0(); } BAR();                     \
    DSA(1, 0); DSB(1, 0); if (SON) STB(0, 128, 0);                               \
    PH_MM(0, 0) BAR();                                                           \
    DSB(1, 1); if (SON) STA(1, 192, 0);                                          \
    PH_MM(0, 1) BAR();                                                           \
    DSA(1, 1); if (SON) STB(1, 192, 1);                                          \
    PH_MM(1, 1) BAR();                                                           \
    DSB(1, 0); if (SON) STA(1, 192, 1);                                          \
    PH_MM(1, 0) if (SON) { VMCN(); } BAR();                                      \
} while (0)

template <int BN, int NTOT, int K, bool EPI1>
__global__ __launch_bounds__(512, 2) void gemm8p_kernel(
    const _Float16* __restrict__ Ap,
    const _Float16* __restrict__ Bp,
    const float* __restrict__ bias,
    const int* __restrict__ tile_expert,
    const int* __restrict__ off, const int* __restrict__ counts,
    _Float16* __restrict__ h1out, float* __restrict__ yout)
{
    constexpr int WARPS_N = BN / 64;          // 4 or 2
    constexpr int WM = 256 / (8 / WARPS_N);   // 128 or 64 rows per wave
    constexpr int MH = WM / 32;               // m-tiles per half-quadrant: 4 or 2
    constexpr int LPB = BN / 128;             // gloads per B half: 2 or 1
    constexpr int BHH = BN * 32;              // halves per B half region
    constexpr int BUFH = 16384 + BN * 64;     // halves per buffer
    constexpr int NT_N = NTOT / BN;
    constexpr int NI = K / 128;               // main iters (2 K-tiles each)

    __shared__ _Float16 smem[2 * BUFH];
    const char* smb = (const char*)smem;

    int bid = blockIdx.x;
    constexpr int CHUNK = (NT256 * NT_N) / 8; // XCD-chunked swizzle (grid % 8 == 0)
    int swz = (bid & 7) * CHUNK + (bid >> 3);
    int mt = swz / NT_N, nt = swz % NT_N;
    int e = tile_expert[mt];
    if (e < 0) return;
    int row0 = mt * 256, n0 = nt * BN;

    int tid = threadIdx.x;
    int lane = tid & 63, wv = tid >> 6;
    int wn = wv % WARPS_N, wm = wv / WARPS_N;
    int lm = lane & 15, kq = lane >> 4;
    int kqx = (kq * 16) ^ (((lm >> 2) & 1) << 5);          // read-side swizzle
    int aob = (wm * (WM / 2) + lm) * 128 + kqx;            // A lds row base (bytes)
    int bob = 32768 + (wn * 32 + lm) * 128 + kqx;          // B lds row base (bytes)

    // staging: dest row j = r*64 + trow (linear); source row = interleave(j)
    int trow = tid >> 3;
    int tcol = ((tid & 7) * 16) ^ (((tid >> 5) & 1) << 5); // source-side swizzle
    int j1 = trow + 64;
    int oa0 = (trow / (WM / 2)) * WM + (trow % (WM / 2));
    int oa1 = (j1 / (WM / 2)) * WM + (j1 % (WM / 2));
    int ob0 = (trow >> 5) * 64 + (trow & 31);
    int ob1 = (j1 >> 5) * 64 + (j1 & 31);
    const _Float16* gA0 = Ap + ((size_t)(row0 + oa0)) * K + (tcol >> 1);
    const _Float16* gA1 = Ap + ((size_t)(row0 + oa1)) * K + (tcol >> 1);
    const _Float16* gB0 = Bp + ((size_t)e * NTOT + n0 + ob0) * K + (tcol >> 1);
    const _Float16* gB1 = (LPB == 2) ? Bp + ((size_t)e * NTOT + n0 + ob1) * K + (tcol >> 1)
                                     : gB0;

    floatx4 acc[2 * MH][4] = {};
    f16x8 af[MH][2], bf[2][2];

    // prologue: kt0 full + kt1 minus B.h0 (staged at iter0 ph1)
    STA(0, 0, 0); STA(0, 0, 1); STB(0, 0, 0); STB(0, 0, 1);
    STA(1, 64, 0); STB(1, 64, 1); STA(1, 64, 1);
    VMC0(); BAR();

#pragma unroll 1
    for (int i = 0; i < NI - 1; ++i) {
        ITER(1);
        gA0 += 128; gA1 += 128; gB0 += 128; gB1 += 128;
    }
    ITER(0);

    if constexpr (EPI1) {
        // bias + gelu + fp16 repack + 16B coalesced H1 stores
        const float* be = bias + (size_t)e * NTOT + n0 + wn * 64;
        float bb[4];
#pragma unroll
        for (int ni = 0; ni < 4; ++ni) bb[ni] = be[ni * 16 + lm];
        _Float16* wbuf = smem + wv * (16 * 72);
        int rowg0 = row0 + wm * WM;
        int colg0 = n0 + wn * 64;
#pragma unroll
        for (int mi = 0; mi < 2 * MH; ++mi) {
#pragma unroll
            for (int ni = 0; ni < 4; ++ni)
#pragma unroll
                for (int r = 0; r < 4; ++r)
                    wbuf[(kq * 4 + r) * 72 + ni * 16 + lm] =
                        (_Float16)gelu_f(acc[mi][ni][r] + bb[ni]);
#pragma unroll
            for (int i2 = 0; i2 < 2; ++i2) {
                int idx = i2 * 64 + lane;
                int rr = idx >> 3, cc = (idx & 7) * 8;
                *(f16x8*)(h1out + (size_t)(rowg0 + mi * 16 + rr) * NTOT + colg0 + cc) =
                    *(const f16x8*)(wbuf + rr * 72 + cc);
            }
        }
    } else {
        int end = off[e] + counts[e];
#pragma unroll
        for (int mi = 0; mi < 2 * MH; ++mi) {
            int rbase = row0 + wm * WM + mi * 16 + kq * 4;
#pragma unroll
            for (int r = 0; r < 4; ++r) {
                int s = rbase + r;
                if (s >= end) continue;        // pad rows never read
#pragma unroll
                for (int ni = 0; ni < 4; ++ni) {
                    int d = n0 + wn * 64 + ni * 16 + lm;
                    yout[(size_t)s * NTOT + d] = acc[mi][ni][r];
                }
            }
        }
    }
}

#undef ITER
#undef PH_MM
#undef MM
#undef STB
#undef STA
#undef DSB
#undef DSA
#undef VMCN
#undef VMC0
#undef SCB
#undef WAITLGKM
#undef BAR

// ---------------- Combine: out[t] = sum_k wts[t,k] * (y[slot_k] + b2[e_k]) ----------------
__global__ __launch_bounds__(256) void combine_kernel(
    const float* __restrict__ y, const int* __restrict__ slot_of,
    const float* __restrict__ wts, const int* __restrict__ sel,
    const float* __restrict__ b2, float* __restrict__ out)
{
    int t = blockIdx.x, i = threadIdx.x;
    int s0 = slot_of[2*t], s1 = slot_of[2*t+1];
    int e0 = sel[2*t], e1 = sel[2*t+1];
    float w0 = wts[2*t], w1 = wts[2*t+1];
    float4 y0 = ((const float4*)(y + (size_t)s0 * DIM))[i];
    float4 y1 = ((const float4*)(y + (size_t)s1 * DIM))[i];
    float4 c0 = ((const float4*)(b2 + (size_t)e0 * DIM))[i];
    float4 c1 = ((const float4*)(b2 + (size_t)e1 * DIM))[i];
    float4 o;
    o.x = w0 * (y0.x + c0.x) + w1 * (y1.x + c1.x);
    o.y = w0 * (y0.y + c0.y) + w1 * (y1.y + c1.y);
    o.z = w0 * (y0.z + c0.z) + w1 * (y1.z + c1.z);
    o.w = w0 * (y0.w + c0.w) + w1 * (y1.w + c1.w);
    ((float4*)(out + (size_t)t * DIM))[i] = o;
}

extern "C" void kernel_launch(void* const* d_in, const int* in_sizes, int n_in,
                              void* d_out, int out_size, void* d_ws, size_t ws_size,
                              hipStream_t stream)
{
    const float* x    = (const float*)d_in[0];
    const float* gw   = (const float*)d_in[1];
    const float* ln_s = (const float*)d_in[2];
    const float* ln_b = (const float*)d_in[3];
    const float* w1   = (const float*)d_in[4];
    const float* b1   = (const float*)d_in[5];
    const float* w2   = (const float*)d_in[6];
    const float* b2   = (const float*)d_in[7];
    float* out = (float*)d_out;

    char* p = (char*)d_ws;
    auto carve = [&](size_t bytes) -> char* {
        char* r = p;
        p += (bytes + 255) & ~(size_t)255;
        return r;
    };
    int*   counts   = (int*)carve(NE * 4);
    int*   cursor   = (int*)carve(NE * 4);
    int*   off      = (int*)carve((NE + 1) * 4);
    int*   tile_exp = (int*)carve(NT256 * 4);
    int*   sel      = (int*)carve((size_t)T_TOK * 2 * 4);
    float* wts      = (float*)carve((size_t)T_TOK * 2 * 4);
    float* mu_arr   = (float*)carve((size_t)T_TOK * 4);
    float* rstd_arr = (float*)carve((size_t)T_TOK * 4);
    int*   slot_of  = (int*)carve((size_t)T_TOK * 2 * 4);
    _Float16* xg  = (_Float16*)carve((size_t)CAP_ROWS * DIM * 2);  // 37.7 MB
    _Float16* w1t = (_Float16*)carve((size_t)NE * DIM * HID * 2);  // 67.1 MB
    _Float16* w2t = (_Float16*)carve((size_t)NE * DIM * HID * 2);
    _Float16* H1  = (_Float16*)carve((size_t)CAP_ROWS * HID * 2);  // 151 MB
    // y (75.5 MB fp32) aliases xg+w1t (104.8 MB) — both dead after gemm1
    float* y = (float*)xg;

    hipMemsetAsync(counts, 0, NE * 4, stream);

    gating_ln_kernel<<<T_TOK, 256, 0, stream>>>(x, gw, sel, wts, mu_arr, rstd_arr, counts);
    build_offsets_kernel<<<1, 256, 0, stream>>>(counts, off, cursor, tile_exp);
    scatter_kernel<<<T_TOK, 256, 0, stream>>>(x, ln_s, ln_b, sel, mu_arr, rstd_arr,
                                              off, cursor, xg, slot_of);
    transpose_cvt_kernel<<<dim3(HID/64, DIM/64, NE), 256, 0, stream>>>(w1, w1t, DIM, HID);
    transpose_cvt_kernel<<<dim3(DIM/64, HID/64, NE), 256, 0, stream>>>(w2, w2t, HID, DIM);

    // GEMM1: H1 = gelu(xg @ w1 + b1)   [256x256 tiles, K=1024]
    gemm8p_kernel<256, HID, DIM, true><<<NT256 * (HID / 256), 512, 0, stream>>>(
        xg, w1t, b1, tile_exp, off, counts, H1, nullptr);
    // GEMM2: y = H1 @ w2               [256x128 tiles, K=4096]
    gemm8p_kernel<128, DIM, HID, false><<<NT256 * (DIM / 128), 512, 0, stream>>>(
        H1, w2t, nullptr, tile_exp, off, counts, nullptr, y);

    combine_kernel<<<T_TOK, 256, 0, stream>>>(y, slot_of, wts, sel, b2, out);
}

// Round 3
// 1138.260 us; speedup vs baseline: 1.0201x; 1.0201x over previous
//
#include <hip/hip_runtime.h>
#include <hip/hip_bf16.h>
#include <hip/hip_fp16.h>
#include <math.h>

#define T_TOK 8192
#define DIM   1024
#define HID   4096
#define NE    8
#define NT256 72                    // max 256-row slabs: 16384 + 8*255 <= 72*256
#define CAP_ROWS (NT256 * 256)      // 18432 padded slots

typedef _Float16 f16x8 __attribute__((ext_vector_type(8)));
typedef float    floatx4 __attribute__((ext_vector_type(4)));

__device__ __forceinline__ void gload_lds16(const void* g, void* l) {
    __builtin_amdgcn_global_load_lds(
        (const __attribute__((address_space(1))) void*)g,
        (__attribute__((address_space(3))) void*)l,
        16, 0, 0);
}

// tanh-form GELU (max dev from exact ~1e-3)
__device__ __forceinline__ float gelu_f(float v) {
    float u = v * (0.7978845608028654f + 0.03567740813636141f * v * v);
    float e = exp2f(2.8853900817779268f * u);     // exp(2u)
    float th = 1.f - 2.f / (e + 1.f);
    return 0.5f * v * (1.f + th);
}

// ---------------- Pass 1a: gating + LN stats ----------------
__global__ __launch_bounds__(256) void gating_ln_kernel(
    const float* __restrict__ x, const float* __restrict__ gw,
    int* __restrict__ sel, float* __restrict__ wts,
    float* __restrict__ mu_arr, float* __restrict__ rstd_arr,
    int* __restrict__ counts)
{
    int t = blockIdx.x;
    int tid = threadIdx.x;
    float4 xv = ((const float4*)(x + (size_t)t * DIM))[tid];
    float s  = xv.x + xv.y + xv.z + xv.w;
    float ss = xv.x*xv.x + xv.y*xv.y + xv.z*xv.z + xv.w*xv.w;
    float l[NE];
#pragma unroll
    for (int e = 0; e < NE; e++) l[e] = 0.f;
    int d0 = tid * 4;
    const float* xp = &xv.x;
#pragma unroll
    for (int j = 0; j < 4; j++) {
        float xj = xp[j];
        const float4* g = (const float4*)(gw + (size_t)(d0 + j) * NE);
        float4 g0 = g[0], g1 = g[1];
        l[0] += xj * g0.x; l[1] += xj * g0.y; l[2] += xj * g0.z; l[3] += xj * g0.w;
        l[4] += xj * g1.x; l[5] += xj * g1.y; l[6] += xj * g1.z; l[7] += xj * g1.w;
    }
#pragma unroll
    for (int off = 32; off > 0; off >>= 1) {
        s  += __shfl_down(s, off);
        ss += __shfl_down(ss, off);
#pragma unroll
        for (int e = 0; e < NE; e++) l[e] += __shfl_down(l[e], off);
    }
    __shared__ float red[4][10];
    int lane = tid & 63, wv = tid >> 6;
    if (lane == 0) {
        red[wv][0] = s; red[wv][1] = ss;
        for (int e = 0; e < NE; e++) red[wv][2 + e] = l[e];
    }
    __syncthreads();
    if (tid == 0) {
        float S = 0.f, SS = 0.f, L[NE];
        for (int e = 0; e < NE; e++) L[e] = 0.f;
        for (int w = 0; w < 4; w++) {
            S += red[w][0]; SS += red[w][1];
            for (int e = 0; e < NE; e++) L[e] += red[w][2 + e];
        }
        float mu  = S * (1.f / DIM);
        float var = SS * (1.f / DIM) - mu * mu;
        float rstd = rsqrtf(var + 1e-5f);
        float lmax = L[0];
        for (int e = 1; e < NE; e++) lmax = fmaxf(lmax, L[e]);
        float den = 0.f;
        for (int e = 0; e < NE; e++) den += expf(L[e] - lmax);
        int i0 = 0; float b0 = L[0];
        for (int e = 1; e < NE; e++) if (L[e] > b0) { b0 = L[e]; i0 = e; }
        int i1 = -1; float b1v = -3.4e38f;
        for (int e = 0; e < NE; e++) if (e != i0 && L[e] > b1v) { b1v = L[e]; i1 = e; }
        float p0 = expf(b0 - lmax) / den;
        float p1 = expf(b1v - lmax) / den;
        float t1 = expf(p1 - p0);            // p1 <= p0, stable
        float w0 = 1.f / (1.f + t1);
        float w1 = t1 / (1.f + t1);
        sel[2*t] = i0;  sel[2*t+1] = i1;
        wts[2*t] = w0;  wts[2*t+1] = w1;
        mu_arr[t] = mu; rstd_arr[t] = rstd;
        atomicAdd(&counts[i0], 1);
        atomicAdd(&counts[i1], 1);
    }
}

// ---------------- Pass 1b: 256-aligned offsets + tile->expert map (parallel) ----------------
__global__ __launch_bounds__(256) void build_offsets_kernel(
    const int* __restrict__ counts, int* __restrict__ off,
    int* __restrict__ cursor, int* __restrict__ tile_expert)
{
    __shared__ int soff[NE + 1];
    int tid = threadIdx.x;
    if (tid == 0) {
        int o = 0;
        for (int e = 0; e < NE; e++) {
            off[e] = soff[e] = o;
            o += ((counts[e] + 255) >> 8) << 8;
            cursor[e] = 0;
        }
        off[NE] = soff[NE] = o;
    }
    __syncthreads();
    int o = soff[NE];
    for (int i = tid; i < NT256; i += 256) {
        int pos = i * 256, e = -1;
        if (pos < o) {
            for (int j = 0; j < NE; j++)
                if (pos >= soff[j] && pos < soff[j + 1]) { e = j; break; }
        }
        tile_expert[i] = e;
    }
}

// ---------------- Pass 1c: scatter normalized tokens (LN affine folded) ----------------
__global__ __launch_bounds__(256) void scatter_kernel(
    const float* __restrict__ x, const float* __restrict__ ln_s, const float* __restrict__ ln_b,
    const int* __restrict__ sel,
    const float* __restrict__ mu_arr, const float* __restrict__ rstd_arr,
    const int* __restrict__ off, int* __restrict__ cursor,
    _Float16* __restrict__ xg, int* __restrict__ slot_of)
{
    int t = blockIdx.x, tid = threadIdx.x;
    __shared__ int sslot[2];
    int e0 = sel[2*t], e1 = sel[2*t+1];
    if (tid == 0) {
        int s0 = off[e0] + atomicAdd(&cursor[e0], 1);
        int s1 = off[e1] + atomicAdd(&cursor[e1], 1);
        sslot[0] = s0; sslot[1] = s1;
        slot_of[2*t] = s0; slot_of[2*t+1] = s1;
    }
    __syncthreads();
    float4 xv = ((const float4*)(x + (size_t)t * DIM))[tid];
    float mu = mu_arr[t], rstd = rstd_arr[t];
    float xn0 = (xv.x - mu) * rstd, xn1 = (xv.y - mu) * rstd;
    float xn2 = (xv.z - mu) * rstd, xn3 = (xv.w - mu) * rstd;
#pragma unroll
    for (int k = 0; k < 2; k++) {
        int e = (k == 0) ? e0 : e1;
        int slot = sslot[k];
        float4 sv = ((const float4*)(ln_s + (size_t)e * DIM))[tid];
        float4 bv = ((const float4*)(ln_b + (size_t)e * DIM))[tid];
        _Float16 hb[4];
        hb[0] = (_Float16)(xn0 * sv.x + bv.x);
        hb[1] = (_Float16)(xn1 * sv.y + bv.y);
        hb[2] = (_Float16)(xn2 * sv.z + bv.z);
        hb[3] = (_Float16)(xn3 * sv.w + bv.w);
        *(uint2*)(xg + (size_t)slot * DIM + tid * 4) = *(const uint2*)hb;
    }
}

// ---------------- Weight transpose + fp32->fp16 convert ----------------
__global__ __launch_bounds__(256) void transpose_cvt_kernel(
    const float* __restrict__ in, _Float16* __restrict__ out, int R, int C)
{
    __shared__ _Float16 tile[64][65];
    size_t ebase = (size_t)blockIdx.z * R * C;
    const float* inp = in + ebase + (size_t)(blockIdx.y * 64) * C + blockIdx.x * 64;
    _Float16* outp = out + ebase + (size_t)(blockIdx.x * 64) * R + blockIdx.y * 64;
    int t = threadIdx.x & 31, j0 = threadIdx.x >> 5;
    for (int j = j0; j < 64; j += 8) {
        float2 v = *(const float2*)(inp + (size_t)j * C + 2 * t);
        tile[j][2*t]   = (_Float16)v.x;
        tile[j][2*t+1] = (_Float16)v.y;
    }
    __syncthreads();
    for (int j = j0; j < 64; j += 8) {
        _Float16 pr[2] = { tile[2*t][j], tile[2*t+1][j] };
        *(unsigned int*)(outp + (size_t)j * R + 2 * t) = *(unsigned int*)pr;
    }
}

// ================= 8-phase 256-row-tile GEMM (T2+T3+T4+T5) =================
// BM=256, BK=64, 512 threads (8 waves, 2 waves/SIMD, 1 block/CU).
// A = [rows][K] fp16 (xg or H1); B = [N][K] fp16 (pre-transposed weights).
// LDS: 2 buffers x (A 32KB + B BN*128B). Halves are wave-interleaved so each
// staged 8KB chunk is exactly the data one phase's ds_reads consume.
// Bank swizzle (128B rows, b128 reads): byte ^= (row&7)<<4 — 3-bit XOR spreads
// each 8-row stripe across all 32 banks. Applied on the global SOURCE col for
// the linear-dest gload_lds and on the ds_read col (same involution, rule 21).
// Second k-fragment address is kx0^64 (NOT +64) since the XOR touches bit 6.

#define BAR() __builtin_amdgcn_s_barrier()
#define WAITLGKM() asm volatile("s_waitcnt lgkmcnt(0)" ::: "memory")
#define SCB() __builtin_amdgcn_sched_barrier(0)
#define VMC0() asm volatile("s_waitcnt vmcnt(0)" ::: "memory")
#define VMCN() do { if (LPB == 2) { asm volatile("s_waitcnt vmcnt(6)" ::: "memory"); } \
                    else          { asm volatile("s_waitcnt vmcnt(5)" ::: "memory"); } } while (0)

#define DSA(B_, MHI) do {                                                        \
    const char* p_ = smb + (B_) * (2 * BUFH) + (MHI) * 16384 + aob;              \
    _Pragma("unroll")                                                            \
    for (int mi_ = 0; mi_ < MH; ++mi_) {                                         \
        af[mi_][0] = *(const f16x8*)(p_ + mi_ * 2048 + kx0);                     \
        af[mi_][1] = *(const f16x8*)(p_ + mi_ * 2048 + kx1);                     \
    }                                                                            \
} while (0)

#define DSB(B_, NHI) do {                                                        \
    const char* p_ = smb + (B_) * (2 * BUFH) + (NHI) * (BN * 64) + bob;          \
    _Pragma("unroll")                                                            \
    for (int tn_ = 0; tn_ < 2; ++tn_) {                                          \
        bf[tn_][0] = *(const f16x8*)(p_ + tn_ * 2048 + kx0);                     \
        bf[tn_][1] = *(const f16x8*)(p_ + tn_ * 2048 + kx1);                     \
    }                                                                            \
} while (0)

#define STA(B_, KOFF, H_) do {                                                   \
    _Float16* d_ = smem + (B_) * BUFH + (H_) * 8192 + tid * 8;                   \
    gload_lds16(gA0 + (size_t)((H_) * (WM / 2)) * K + (KOFF), d_);               \
    gload_lds16(gA1 + (size_t)((H_) * (WM / 2)) * K + (KOFF), d_ + 4096);        \
} while (0)

#define STB(B_, KOFF, H_) do {                                                   \
    _Float16* d_ = smem + (B_) * BUFH + 16384 + (H_) * BHH + tid * 8;            \
    gload_lds16(gB0 + (size_t)((H_) * 32) * K + (KOFF), d_);                     \
    if (LPB == 2) gload_lds16(gB1 + (size_t)((H_) * 32) * K + (KOFF), d_ + 4096);\
} while (0)

#define MM(MHI, NHI) do {                                                        \
    _Pragma("unroll")                                                            \
    for (int mi_ = 0; mi_ < MH; ++mi_) {                                         \
        _Pragma("unroll")                                                        \
        for (int tn_ = 0; tn_ < 2; ++tn_) {                                      \
            floatx4* a_ = &acc[(MHI) * MH + mi_][(NHI) * 2 + tn_];               \
            *a_ = __builtin_amdgcn_mfma_f32_16x16x32_f16(af[mi_][0], bf[tn_][0], *a_, 0, 0, 0); \
            *a_ = __builtin_amdgcn_mfma_f32_16x16x32_f16(af[mi_][1], bf[tn_][1], *a_, 0, 0, 0); \
        }                                                                        \
    }                                                                            \
} while (0)

#define PH_MM(MHI, NHI)                                                          \
    BAR(); WAITLGKM(); SCB();                                                    \
    __builtin_amdgcn_s_setprio(1); MM(MHI, NHI); __builtin_amdgcn_s_setprio(0);

// stage schedule (iter i, K-tiles 2i/2i+1 live, staging 2i+2/2i+3):
// ph1:B1h0(kt2i+1) ph2:A0h0 ph3:B0h1 ph4:A0h1 [vmcnt] ph5:B0h0 ph6:A1h0 ph7:B1h1 ph8:A1h1 [vmcnt]
#define ITER(SON) do {                                                           \
    DSA(0, 0); DSB(0, 0); STB(1, 64, 0);                                         \
    PH_MM(0, 0) BAR();                                                           \
    DSB(0, 1); if (SON) STA(0, 128, 0);                                          \
    PH_MM(0, 1) BAR();                                                           \
    DSA(0, 1); if (SON) STB(0, 128, 1);                                          \
    PH_MM(1, 1) BAR();                                                           \
    DSB(0, 0); if (SON) STA(0, 128, 1);                                          \
    PH_MM(1, 0) if (SON) { VMCN(); } else { VMC0(); } BAR();                     \
    DSA(1, 0); DSB(1, 0); if (SON) STB(0, 128, 0);                               \
    PH_MM(0, 0) BAR();                                                           \
    DSB(1, 1); if (SON) STA(1, 192, 0);                                          \
    PH_MM(0, 1) BAR();                                                           \
    DSA(1, 1); if (SON) STB(1, 192, 1);                                          \
    PH_MM(1, 1) BAR();                                                           \
    DSB(1, 0); if (SON) STA(1, 192, 1);                                          \
    PH_MM(1, 0) if (SON) { VMCN(); } BAR();                                      \
} while (0)

template <int BN, int NTOT, int K, bool EPI1>
__global__ __launch_bounds__(512, 2) void gemm8p_kernel(
    const _Float16* __restrict__ Ap,
    const _Float16* __restrict__ Bp,
    const float* __restrict__ bias,
    const int* __restrict__ tile_expert,
    const int* __restrict__ off, const int* __restrict__ counts,
    _Float16* __restrict__ h1out, float* __restrict__ yout)
{
    constexpr int WARPS_N = BN / 64;          // 4 or 2
    constexpr int WM = 256 / (8 / WARPS_N);   // 128 or 64 rows per wave
    constexpr int MH = WM / 32;               // m-tiles per half-quadrant: 4 or 2
    constexpr int LPB = BN / 128;             // gloads per B half: 2 or 1
    constexpr int BHH = BN * 32;              // halves per B half region
    constexpr int BUFH = 16384 + BN * 64;     // halves per buffer
    constexpr int NT_N = NTOT / BN;
    constexpr int NI = K / 128;               // main iters (2 K-tiles each)

    __shared__ _Float16 smem[2 * BUFH];
    const char* smb = (const char*)smem;

    int bid = blockIdx.x;
    constexpr int CHUNK = (NT256 * NT_N) / 8; // XCD-chunked swizzle (grid % 8 == 0)
    int swz = (bid & 7) * CHUNK + (bid >> 3);
    int mt = swz / NT_N, nt = swz % NT_N;
    int e = tile_expert[mt];
    if (e < 0) return;
    int row0 = mt * 256, n0 = nt * BN;

    int tid = threadIdx.x;
    int lane = tid & 63, wv = tid >> 6;
    int wn = wv % WARPS_N, wm = wv / WARPS_N;
    int lm = lane & 15, kq = lane >> 4;
    int kx0 = (kq * 16) ^ ((lm & 7) << 4);                 // read-side swizzle (bytes)
    int kx1 = kx0 ^ 64;                                    // second k-fragment
    int aob = (wm * (WM / 2) + lm) * 128;                  // A lds row base (bytes)
    int bob = 32768 + (wn * 32 + lm) * 128;                // B lds row base (bytes)

    // staging: dest row j = r*64 + trow (linear); source row = interleave(j)
    int trow = tid >> 3;
    int tcol = ((tid & 7) * 16) ^ ((trow & 7) << 4);       // source-side swizzle
    int j1 = trow + 64;
    int oa0 = (trow / (WM / 2)) * WM + (trow % (WM / 2));
    int oa1 = (j1 / (WM / 2)) * WM + (j1 % (WM / 2));
    int ob0 = (trow >> 5) * 64 + (trow & 31);
    int ob1 = (j1 >> 5) * 64 + (j1 & 31);
    const _Float16* gA0 = Ap + ((size_t)(row0 + oa0)) * K + (tcol >> 1);
    const _Float16* gA1 = Ap + ((size_t)(row0 + oa1)) * K + (tcol >> 1);
    const _Float16* gB0 = Bp + ((size_t)e * NTOT + n0 + ob0) * K + (tcol >> 1);
    const _Float16* gB1 = (LPB == 2) ? Bp + ((size_t)e * NTOT + n0 + ob1) * K + (tcol >> 1)
                                     : gB0;

    floatx4 acc[2 * MH][4] = {};
    f16x8 af[MH][2], bf[2][2];

    // prologue: kt0 full + kt1 minus B.h0 (staged at iter0 ph1)
    STA(0, 0, 0); STA(0, 0, 1); STB(0, 0, 0); STB(0, 0, 1);
    STA(1, 64, 0); STB(1, 64, 1); STA(1, 64, 1);
    VMC0(); BAR();

#pragma unroll 1
    for (int i = 0; i < NI - 1; ++i) {
        ITER(1);
        gA0 += 128; gA1 += 128; gB0 += 128; gB1 += 128;
    }
    ITER(0);

    if constexpr (EPI1) {
        // bias + gelu + fp16 repack + 16B coalesced H1 stores
        const float* be = bias + (size_t)e * NTOT + n0 + wn * 64;
        float bb[4];
#pragma unroll
        for (int ni = 0; ni < 4; ++ni) bb[ni] = be[ni * 16 + lm];
        _Float16* wbuf = smem + wv * (16 * 72);
        int rowg0 = row0 + wm * WM;
        int colg0 = n0 + wn * 64;
#pragma unroll
        for (int mi = 0; mi < 2 * MH; ++mi) {
#pragma unroll
            for (int ni = 0; ni < 4; ++ni)
#pragma unroll
                for (int r = 0; r < 4; ++r)
                    wbuf[(kq * 4 + r) * 72 + ni * 16 + lm] =
                        (_Float16)gelu_f(acc[mi][ni][r] + bb[ni]);
#pragma unroll
            for (int i2 = 0; i2 < 2; ++i2) {
                int idx = i2 * 64 + lane;
                int rr = idx >> 3, cc = (idx & 7) * 8;
                *(f16x8*)(h1out + (size_t)(rowg0 + mi * 16 + rr) * NTOT + colg0 + cc) =
                    *(const f16x8*)(wbuf + rr * 72 + cc);
            }
        }
    } else {
        int end = off[e] + counts[e];
#pragma unroll
        for (int mi = 0; mi < 2 * MH; ++mi) {
            int rbase = row0 + wm * WM + mi * 16 + kq * 4;
#pragma unroll
            for (int r = 0; r < 4; ++r) {
                int s = rbase + r;
                if (s >= end) continue;        // pad rows never read
#pragma unroll
                for (int ni = 0; ni < 4; ++ni) {
                    int d = n0 + wn * 64 + ni * 16 + lm;
                    yout[(size_t)s * NTOT + d] = acc[mi][ni][r];
                }
            }
        }
    }
}

#undef ITER
#undef PH_MM
#undef MM
#undef STB
#undef STA
#undef DSB
#undef DSA
#undef VMCN
#undef VMC0
#undef SCB
#undef WAITLGKM
#undef BAR

// ---------------- Combine: out[t] = sum_k wts[t,k] * (y[slot_k] + b2[e_k]) ----------------
__global__ __launch_bounds__(256) void combine_kernel(
    const float* __restrict__ y, const int* __restrict__ slot_of,
    const float* __restrict__ wts, const int* __restrict__ sel,
    const float* __restrict__ b2, float* __restrict__ out)
{
    int t = blockIdx.x, i = threadIdx.x;
    int s0 = slot_of[2*t], s1 = slot_of[2*t+1];
    int e0 = sel[2*t], e1 = sel[2*t+1];
    float w0 = wts[2*t], w1 = wts[2*t+1];
    float4 y0 = ((const float4*)(y + (size_t)s0 * DIM))[i];
    float4 y1 = ((const float4*)(y + (size_t)s1 * DIM))[i];
    float4 c0 = ((const float4*)(b2 + (size_t)e0 * DIM))[i];
    float4 c1 = ((const float4*)(b2 + (size_t)e1 * DIM))[i];
    float4 o;
    o.x = w0 * (y0.x + c0.x) + w1 * (y1.x + c1.x);
    o.y = w0 * (y0.y + c0.y) + w1 * (y1.y + c1.y);
    o.z = w0 * (y0.z + c0.z) + w1 * (y1.z + c1.z);
    o.w = w0 * (y0.w + c0.w) + w1 * (y1.w + c1.w);
    ((float4*)(out + (size_t)t * DIM))[i] = o;
}

extern "C" void kernel_launch(void* const* d_in, const int* in_sizes, int n_in,
                              void* d_out, int out_size, void* d_ws, size_t ws_size,
                              hipStream_t stream)
{
    const float* x    = (const float*)d_in[0];
    const float* gw   = (const float*)d_in[1];
    const float* ln_s = (const float*)d_in[2];
    const float* ln_b = (const float*)d_in[3];
    const float* w1   = (const float*)d_in[4];
    const float* b1   = (const float*)d_in[5];
    const float* w2   = (const float*)d_in[6];
    const float* b2   = (const float*)d_in[7];
    float* out = (float*)d_out;

    char* p = (char*)d_ws;
    auto carve = [&](size_t bytes) -> char* {
        char* r = p;
        p += (bytes + 255) & ~(size_t)255;
        return r;
    };
    int*   counts   = (int*)carve(NE * 4);
    int*   cursor   = (int*)carve(NE * 4);
    int*   off      = (int*)carve((NE + 1) * 4);
    int*   tile_exp = (int*)carve(NT256 * 4);
    int*   sel      = (int*)carve((size_t)T_TOK * 2 * 4);
    float* wts      = (float*)carve((size_t)T_TOK * 2 * 4);
    float* mu_arr   = (float*)carve((size_t)T_TOK * 4);
    float* rstd_arr = (float*)carve((size_t)T_TOK * 4);
    int*   slot_of  = (int*)carve((size_t)T_TOK * 2 * 4);
    _Float16* xg  = (_Float16*)carve((size_t)CAP_ROWS * DIM * 2);  // 37.7 MB
    _Float16* w1t = (_Float16*)carve((size_t)NE * DIM * HID * 2);  // 67.1 MB
    _Float16* w2t = (_Float16*)carve((size_t)NE * DIM * HID * 2);
    _Float16* H1  = (_Float16*)carve((size_t)CAP_ROWS * HID * 2);  // 151 MB
    // y (75.5 MB fp32) aliases xg+w1t (104.8 MB) — both dead after gemm1
    float* y = (float*)xg;

    hipMemsetAsync(counts, 0, NE * 4, stream);

    gating_ln_kernel<<<T_TOK, 256, 0, stream>>>(x, gw, sel, wts, mu_arr, rstd_arr, counts);
    build_offsets_kernel<<<1, 256, 0, stream>>>(counts, off, cursor, tile_exp);
    scatter_kernel<<<T_TOK, 256, 0, stream>>>(x, ln_s, ln_b, sel, mu_arr, rstd_arr,
                                              off, cursor, xg, slot_of);
    transpose_cvt_kernel<<<dim3(HID/64, DIM/64, NE), 256, 0, stream>>>(w1, w1t, DIM, HID);
    transpose_cvt_kernel<<<dim3(DIM/64, HID/64, NE), 256, 0, stream>>>(w2, w2t, HID, DIM);

    // GEMM1: H1 = gelu(xg @ w1 + b1)   [256x256 tiles, K=1024]
    gemm8p_kernel<256, HID, DIM, true><<<NT256 * (HID / 256), 512, 0, stream>>>(
        xg, w1t, b1, tile_exp, off, counts, H1, nullptr);
    // GEMM2: y = H1 @ w2               [256x128 tiles, K=4096]
    gemm8p_kernel<128, DIM, HID, false><<<NT256 * (DIM / 128), 512, 0, stream>>>(
        H1, w2t, nullptr, tile_exp, off, counts, nullptr, y);

    combine_kernel<<<T_TOK, 256, 0, stream>>>(y, slot_of, wts, sel, b2, out);
}

// Round 4
// 795.375 us; speedup vs baseline: 1.4598x; 1.4311x over previous
//
#include <hip/hip_runtime.h>
#include <hip/hip_bf16.h>
#include <hip/hip_fp16.h>
#include <math.h>

#define T_TOK 8192
#define DIM   1024
#define HID   4096
#define NE    8
#define NT256 72                    // max 256-row slabs: 16384 + 8*255 <= 72*256
#define CAP_ROWS (NT256 * 256)      // 18432 padded slots

typedef _Float16 f16x8 __attribute__((ext_vector_type(8)));
typedef float    floatx4 __attribute__((ext_vector_type(4)));

__device__ __forceinline__ void gload_lds16(const void* g, void* l) {
    __builtin_amdgcn_global_load_lds(
        (const __attribute__((address_space(1))) void*)g,
        (__attribute__((address_space(3))) void*)l,
        16, 0, 0);
}

// tanh-form GELU (max dev from exact ~1e-3)
__device__ __forceinline__ float gelu_f(float v) {
    float u = v * (0.7978845608028654f + 0.03567740813636141f * v * v);
    float e = exp2f(2.8853900817779268f * u);     // exp(2u)
    float th = 1.f - 2.f / (e + 1.f);
    return 0.5f * v * (1.f + th);
}

// ---------------- Pass 1a: gating + LN stats (no atomics) ----------------
__global__ __launch_bounds__(256) void gating_ln_kernel(
    const float* __restrict__ x, const float* __restrict__ gw,
    int* __restrict__ sel, float* __restrict__ wts,
    float* __restrict__ mu_arr, float* __restrict__ rstd_arr)
{
    int t = blockIdx.x;
    int tid = threadIdx.x;
    float4 xv = ((const float4*)(x + (size_t)t * DIM))[tid];
    float s  = xv.x + xv.y + xv.z + xv.w;
    float ss = xv.x*xv.x + xv.y*xv.y + xv.z*xv.z + xv.w*xv.w;
    float l[NE];
#pragma unroll
    for (int e = 0; e < NE; e++) l[e] = 0.f;
    int d0 = tid * 4;
    const float* xp = &xv.x;
#pragma unroll
    for (int j = 0; j < 4; j++) {
        float xj = xp[j];
        const float4* g = (const float4*)(gw + (size_t)(d0 + j) * NE);
        float4 g0 = g[0], g1 = g[1];
        l[0] += xj * g0.x; l[1] += xj * g0.y; l[2] += xj * g0.z; l[3] += xj * g0.w;
        l[4] += xj * g1.x; l[5] += xj * g1.y; l[6] += xj * g1.z; l[7] += xj * g1.w;
    }
#pragma unroll
    for (int off = 32; off > 0; off >>= 1) {
        s  += __shfl_down(s, off);
        ss += __shfl_down(ss, off);
#pragma unroll
        for (int e = 0; e < NE; e++) l[e] += __shfl_down(l[e], off);
    }
    __shared__ float red[4][10];
    int lane = tid & 63, wv = tid >> 6;
    if (lane == 0) {
        red[wv][0] = s; red[wv][1] = ss;
        for (int e = 0; e < NE; e++) red[wv][2 + e] = l[e];
    }
    __syncthreads();
    if (tid == 0) {
        float S = 0.f, SS = 0.f, L[NE];
        for (int e = 0; e < NE; e++) L[e] = 0.f;
        for (int w = 0; w < 4; w++) {
            S += red[w][0]; SS += red[w][1];
            for (int e = 0; e < NE; e++) L[e] += red[w][2 + e];
        }
        float mu  = S * (1.f / DIM);
        float var = SS * (1.f / DIM) - mu * mu;
        float rstd = rsqrtf(var + 1e-5f);
        float lmax = L[0];
        for (int e = 1; e < NE; e++) lmax = fmaxf(lmax, L[e]);
        float den = 0.f;
        for (int e = 0; e < NE; e++) den += expf(L[e] - lmax);
        int i0 = 0; float b0 = L[0];
        for (int e = 1; e < NE; e++) if (L[e] > b0) { b0 = L[e]; i0 = e; }
        int i1 = -1; float b1v = -3.4e38f;
        for (int e = 0; e < NE; e++) if (e != i0 && L[e] > b1v) { b1v = L[e]; i1 = e; }
        float p0 = expf(b0 - lmax) / den;
        float p1 = expf(b1v - lmax) / den;
        float t1 = expf(p1 - p0);            // p1 <= p0, stable
        float w0 = 1.f / (1.f + t1);
        float w1 = t1 / (1.f + t1);
        sel[2*t] = i0;  sel[2*t+1] = i1;
        wts[2*t] = w0;  wts[2*t+1] = w1;
        mu_arr[t] = mu; rstd_arr[t] = rstd;
    }
}

// ---------------- Pass 1b-i: per-block histogram + local ranks (atomic-free) ----------------
__global__ __launch_bounds__(256) void hist_kernel(
    const int* __restrict__ sel, int* __restrict__ blockhist,
    unsigned short* __restrict__ lrank)
{
    int b = blockIdx.x, tid = threadIdx.x;
    int t = b * 256 + tid;
    int e0 = sel[2*t], e1 = sel[2*t+1];
    int lane = tid & 63, w = tid >> 6;
    __shared__ int c0[4][NE], c1[4][NE];
    unsigned long long below = (1ull << lane) - 1ull;
    int r0 = 0, r1 = 0;
#pragma unroll
    for (int e = 0; e < NE; e++) {
        unsigned long long m0 = __ballot(e0 == e);
        unsigned long long m1 = __ballot(e1 == e);
        if (lane == 0) { c0[w][e] = __popcll(m0); c1[w][e] = __popcll(m1); }
        if (e0 == e) r0 = __popcll(m0 & below);
        if (e1 == e) r1 = __popcll(m1 & below);
    }
    __syncthreads();
    int base0 = 0, base1 = 0;
#pragma unroll
    for (int wp = 0; wp < 4; wp++) {
        if (wp < w) { base0 += c0[wp][e0]; base1 += c1[wp][e1]; }
        base1 += c0[wp][e1];          // e1-stream ranks after all e0-stream picks
    }
    lrank[2*t]   = (unsigned short)(base0 + r0);
    lrank[2*t+1] = (unsigned short)(base1 + r1);
    if (tid < NE) {
        int sum = 0;
        for (int wp = 0; wp < 4; wp++) sum += c0[wp][tid] + c1[wp][tid];
        blockhist[b * NE + tid] = sum;
    }
}

// ---------------- Pass 1b-ii: scan blocks, 256-aligned offsets, tile map ----------------
__global__ __launch_bounds__(256) void scan_kernel(
    const int* __restrict__ blockhist, int* __restrict__ off, int* __restrict__ counts,
    int* __restrict__ babs, int* __restrict__ tile_expert)
{
    __shared__ int soff[NE + 1];
    __shared__ int stot[NE];
    int tid = threadIdx.x;
    if (tid < NE) {
        int tot = 0;
        for (int b = 0; b < 32; b++) tot += blockhist[b * NE + tid];
        stot[tid] = tot; counts[tid] = tot;
    }
    __syncthreads();
    if (tid == 0) {
        int o = 0;
        for (int e = 0; e < NE; e++) { soff[e] = o; off[e] = o; o += ((stot[e] + 255) >> 8) << 8; }
        soff[NE] = o; off[NE] = o;
    }
    __syncthreads();
    if (tid < NE) {
        int run = soff[tid];
        for (int b = 0; b < 32; b++) { babs[b * NE + tid] = run; run += blockhist[b * NE + tid]; }
    }
    int o = soff[NE];
    for (int i = tid; i < NT256; i += 256) {
        int pos = i * 256, e = -1;
        if (pos < o) {
            for (int j = 0; j < NE; j++)
                if (pos >= soff[j] && pos < soff[j + 1]) { e = j; break; }
        }
        tile_expert[i] = e;
    }
}

// ---------------- Pass 1c: scatter normalized tokens (atomic-free) ----------------
__global__ __launch_bounds__(256) void scatter_kernel(
    const float* __restrict__ x, const float* __restrict__ ln_s, const float* __restrict__ ln_b,
    const int* __restrict__ sel,
    const float* __restrict__ mu_arr, const float* __restrict__ rstd_arr,
    const int* __restrict__ babs, const unsigned short* __restrict__ lrank,
    _Float16* __restrict__ xg, int* __restrict__ slot_of)
{
    int t = blockIdx.x, tid = threadIdx.x;
    int b = t >> 8;
    int e0 = sel[2*t], e1 = sel[2*t+1];
    int s0 = babs[b * NE + e0] + (int)lrank[2*t];
    int s1 = babs[b * NE + e1] + (int)lrank[2*t+1];
    if (tid == 0) { slot_of[2*t] = s0; slot_of[2*t+1] = s1; }
    float4 xv = ((const float4*)(x + (size_t)t * DIM))[tid];
    float mu = mu_arr[t], rstd = rstd_arr[t];
    float xn0 = (xv.x - mu) * rstd, xn1 = (xv.y - mu) * rstd;
    float xn2 = (xv.z - mu) * rstd, xn3 = (xv.w - mu) * rstd;
#pragma unroll
    for (int k = 0; k < 2; k++) {
        int e = (k == 0) ? e0 : e1;
        int slot = (k == 0) ? s0 : s1;
        float4 sv = ((const float4*)(ln_s + (size_t)e * DIM))[tid];
        float4 bv = ((const float4*)(ln_b + (size_t)e * DIM))[tid];
        _Float16 hb[4];
        hb[0] = (_Float16)(xn0 * sv.x + bv.x);
        hb[1] = (_Float16)(xn1 * sv.y + bv.y);
        hb[2] = (_Float16)(xn2 * sv.z + bv.z);
        hb[3] = (_Float16)(xn3 * sv.w + bv.w);
        *(uint2*)(xg + (size_t)slot * DIM + tid * 4) = *(const uint2*)hb;
    }
}

// ---------------- Weight transpose + fp32->fp16 convert ----------------
__global__ __launch_bounds__(256) void transpose_cvt_kernel(
    const float* __restrict__ in, _Float16* __restrict__ out, int R, int C)
{
    __shared__ _Float16 tile[64][65];
    size_t ebase = (size_t)blockIdx.z * R * C;
    const float* inp = in + ebase + (size_t)(blockIdx.y * 64) * C + blockIdx.x * 64;
    _Float16* outp = out + ebase + (size_t)(blockIdx.x * 64) * R + blockIdx.y * 64;
    int t = threadIdx.x & 31, j0 = threadIdx.x >> 5;
    for (int j = j0; j < 64; j += 8) {
        float2 v = *(const float2*)(inp + (size_t)j * C + 2 * t);
        tile[j][2*t]   = (_Float16)v.x;
        tile[j][2*t+1] = (_Float16)v.y;
    }
    __syncthreads();
    for (int j = j0; j < 64; j += 8) {
        _Float16 pr[2] = { tile[2*t][j], tile[2*t+1][j] };
        *(unsigned int*)(outp + (size_t)j * R + 2 * t) = *(unsigned int*)pr;
    }
}

// ================= 8-phase 256-row-tile GEMM (T2+T3+T4+T5) =================
// r4: one barrier per phase; fine counted-lgkm waits interleave ds-drain with
// MFMA groups (issue order pinned by sched_barrier(0) between read pairs).
// Invariant: every phase ends with lgkmcnt(0) before its last MFMA group, so
// the closing barrier guarantees all waves' reads complete before any wave
// issues the next phase's gload_lds overwrite. Stage/vmcnt schedule unchanged.

#define BAR() __builtin_amdgcn_s_barrier()
#define SCB() __builtin_amdgcn_sched_barrier(0)
#define WLGKM(n) asm volatile("s_waitcnt lgkmcnt(" #n ")" ::: "memory")
#define VMC0() asm volatile("s_waitcnt vmcnt(0)" ::: "memory")
#define VMCN() do { if (LPB == 2) { asm volatile("s_waitcnt vmcnt(6)" ::: "memory"); } \
                    else          { asm volatile("s_waitcnt vmcnt(5)" ::: "memory"); } } while (0)

#define RDA(B_, MHI, MI_) do {                                                   \
    const char* p_ = smb + (B_) * (2 * BUFH) + (MHI) * 16384 + aob;              \
    af[MI_][0] = *(const f16x8*)(p_ + (MI_) * 2048 + kx0);                       \
    af[MI_][1] = *(const f16x8*)(p_ + (MI_) * 2048 + kx1);                       \
} while (0)

#define RDB(B_, NHI, TN_) do {                                                   \
    const char* p_ = smb + (B_) * (2 * BUFH) + (NHI) * (BN * 64) + bob;          \
    bf[TN_][0] = *(const f16x8*)(p_ + (TN_) * 2048 + kx0);                       \
    bf[TN_][1] = *(const f16x8*)(p_ + (TN_) * 2048 + kx1);                       \
} while (0)

#define STA(B_, KOFF, H_) do {                                                   \
    _Float16* d_ = smem + (B_) * BUFH + (H_) * 8192 + tid * 8;                   \
    gload_lds16(gA0 + (size_t)((H_) * (WM / 2)) * K + (KOFF), d_);               \
    gload_lds16(gA1 + (size_t)((H_) * (WM / 2)) * K + (KOFF), d_ + 4096);        \
} while (0)

#define STB(B_, KOFF, H_) do {                                                   \
    _Float16* d_ = smem + (B_) * BUFH + 16384 + (H_) * BHH + tid * 8;            \
    gload_lds16(gB0 + (size_t)((H_) * 32) * K + (KOFF), d_);                     \
    if (LPB == 2) gload_lds16(gB1 + (size_t)((H_) * 32) * K + (KOFF), d_ + 4096);\
} while (0)

#define MMG(MHI, NHI, MI_) do {                                                  \
    floatx4* a0_ = &acc[(MHI) * MH + (MI_)][(NHI) * 2 + 0];                      \
    floatx4* a1_ = &acc[(MHI) * MH + (MI_)][(NHI) * 2 + 1];                      \
    *a0_ = __builtin_amdgcn_mfma_f32_16x16x32_f16(af[MI_][0], bf[0][0], *a0_, 0, 0, 0); \
    *a0_ = __builtin_amdgcn_mfma_f32_16x16x32_f16(af[MI_][1], bf[0][1], *a0_, 0, 0, 0); \
    *a1_ = __builtin_amdgcn_mfma_f32_16x16x32_f16(af[MI_][0], bf[1][0], *a1_, 0, 0, 0); \
    *a1_ = __builtin_amdgcn_mfma_f32_16x16x32_f16(af[MI_][1], bf[1][1], *a1_, 0, 0, 0); \
} while (0)

#define MMT(MHI, NHI, TN_) do {                                                  \
    _Pragma("unroll")                                                            \
    for (int mi_ = 0; mi_ < MH; ++mi_) {                                         \
        floatx4* a_ = &acc[(MHI) * MH + mi_][(NHI) * 2 + (TN_)];                 \
        *a_ = __builtin_amdgcn_mfma_f32_16x16x32_f16(af[mi_][0], bf[TN_][0], *a_, 0, 0, 0); \
        *a_ = __builtin_amdgcn_mfma_f32_16x16x32_f16(af[mi_][1], bf[TN_][1], *a_, 0, 0, 0); \
    }                                                                            \
} while (0)

#define PH_AB(B_, MHI, NHI, ...) do {                                            \
    RDB(B_, NHI, 0); SCB(); RDB(B_, NHI, 1); SCB();                              \
    RDA(B_, MHI, 0); SCB(); RDA(B_, MHI, 1); SCB();                              \
    if constexpr (MH == 4) { RDA(B_, MHI, 2); SCB(); RDA(B_, MHI, 3); SCB(); }   \
    __VA_ARGS__;                                                                 \
    __builtin_amdgcn_s_setprio(1);                                               \
    if constexpr (MH == 4) {                                                     \
        WLGKM(6); SCB(); MMG(MHI, NHI, 0);                                       \
        WLGKM(4); SCB(); MMG(MHI, NHI, 1);                                       \
        WLGKM(2); SCB(); MMG(MHI, NHI, 2);                                       \
        WLGKM(0); SCB(); MMG(MHI, NHI, 3);                                       \
    } else {                                                                     \
        WLGKM(2); SCB(); MMG(MHI, NHI, 0);                                       \
        WLGKM(0); SCB(); MMG(MHI, NHI, 1);                                       \
    }                                                                            \
    __builtin_amdgcn_s_setprio(0);                                               \
} while (0)

#define PH_A(B_, MHI, NHI, ...) do {                                             \
    RDA(B_, MHI, 0); SCB(); RDA(B_, MHI, 1); SCB();                              \
    if constexpr (MH == 4) { RDA(B_, MHI, 2); SCB(); RDA(B_, MHI, 3); SCB(); }   \
    __VA_ARGS__;                                                                 \
    __builtin_amdgcn_s_setprio(1);                                               \
    if constexpr (MH == 4) {                                                     \
        WLGKM(6); SCB(); MMG(MHI, NHI, 0);                                       \
        WLGKM(4); SCB(); MMG(MHI, NHI, 1);                                       \
        WLGKM(2); SCB(); MMG(MHI, NHI, 2);                                       \
        WLGKM(0); SCB(); MMG(MHI, NHI, 3);                                       \
    } else {                                                                     \
        WLGKM(2); SCB(); MMG(MHI, NHI, 0);                                       \
        WLGKM(0); SCB(); MMG(MHI, NHI, 1);                                       \
    }                                                                            \
    __builtin_amdgcn_s_setprio(0);                                               \
} while (0)

#define PH_B(B_, NHI, MHI, ...) do {                                             \
    RDB(B_, NHI, 0); SCB(); RDB(B_, NHI, 1); SCB();                              \
    __VA_ARGS__;                                                                 \
    __builtin_amdgcn_s_setprio(1);                                               \
    WLGKM(2); SCB(); MMT(MHI, NHI, 0);                                           \
    WLGKM(0); SCB(); MMT(MHI, NHI, 1);                                           \
    __builtin_amdgcn_s_setprio(0);                                               \
} while (0)

// stage schedule (iter i, K-tiles 2i/2i+1 live, staging 2i+2/2i+3):
// ph1:B1h0(kt2i+1) ph2:A0h0 ph3:B0h1 ph4:A0h1 [vmcnt] ph5:B0h0 ph6:A1h0 ph7:B1h1 ph8:A1h1 [vmcnt]
#define ITER(SON) do {                                                           \
    PH_AB(0, 0, 0, STB(1, 64, 0)); BAR();                                        \
    PH_B (0, 1, 0, if (SON) STA(0, 128, 0)); BAR();                              \
    PH_A (0, 1, 1, if (SON) STB(0, 128, 1)); BAR();                              \
    PH_B (0, 0, 1, if (SON) STA(0, 128, 1));                                     \
    if (SON) { VMCN(); } else { VMC0(); } BAR();                                 \
    PH_AB(1, 0, 0, if (SON) STB(0, 128, 0)); BAR();                              \
    PH_B (1, 1, 0, if (SON) STA(1, 192, 0)); BAR();                              \
    PH_A (1, 1, 1, if (SON) STB(1, 192, 1)); BAR();                              \
    PH_B (1, 0, 1, if (SON) STA(1, 192, 1));                                     \
    if (SON) { VMCN(); } BAR();                                                  \
} while (0)

template <int BN, int NTOT, int K, bool EPI1>
__global__ __launch_bounds__(512, 2) void gemm8p_kernel(
    const _Float16* __restrict__ Ap,
    const _Float16* __restrict__ Bp,
    const float* __restrict__ bias,
    const int* __restrict__ tile_expert,
    const int* __restrict__ off, const int* __restrict__ counts,
    _Float16* __restrict__ h1out, float* __restrict__ yout)
{
    constexpr int WARPS_N = BN / 64;          // 4 or 2
    constexpr int WM = 256 / (8 / WARPS_N);   // 128 or 64 rows per wave
    constexpr int MH = WM / 32;               // m-tiles per half-quadrant: 4 or 2
    constexpr int LPB = BN / 128;             // gloads per B half: 2 or 1
    constexpr int BHH = BN * 32;              // halves per B half region
    constexpr int BUFH = 16384 + BN * 64;     // halves per buffer
    constexpr int NT_N = NTOT / BN;
    constexpr int NI = K / 128;               // main iters (2 K-tiles each)

    __shared__ _Float16 smem[2 * BUFH];
    const char* smb = (const char*)smem;

    int bid = blockIdx.x;
    constexpr int CHUNK = (NT256 * NT_N) / 8; // XCD-chunked swizzle (grid % 8 == 0)
    int swz = (bid & 7) * CHUNK + (bid >> 3);
    int mt = swz / NT_N, nt = swz % NT_N;
    int e = tile_expert[mt];
    if (e < 0) return;
    int row0 = mt * 256, n0 = nt * BN;

    int tid = threadIdx.x;
    int lane = tid & 63, wv = tid >> 6;
    int wn = wv % WARPS_N, wm = wv / WARPS_N;
    int lm = lane & 15, kq = lane >> 4;
    int kx0 = (kq * 16) ^ ((lm & 7) << 4);                 // read-side swizzle (bytes)
    int kx1 = kx0 ^ 64;                                    // second k-fragment
    int aob = (wm * (WM / 2) + lm) * 128;                  // A lds row base (bytes)
    int bob = 32768 + (wn * 32 + lm) * 128;                // B lds row base (bytes)

    // staging: dest row j = r*64 + trow (linear); source row = interleave(j)
    int trow = tid >> 3;
    int tcol = ((tid & 7) * 16) ^ ((trow & 7) << 4);       // source-side swizzle
    int j1 = trow + 64;
    int oa0 = (trow / (WM / 2)) * WM + (trow % (WM / 2));
    int oa1 = (j1 / (WM / 2)) * WM + (j1 % (WM / 2));
    int ob0 = (trow >> 5) * 64 + (trow & 31);
    int ob1 = (j1 >> 5) * 64 + (j1 & 31);
    const _Float16* gA0 = Ap + ((size_t)(row0 + oa0)) * K + (tcol >> 1);
    const _Float16* gA1 = Ap + ((size_t)(row0 + oa1)) * K + (tcol >> 1);
    const _Float16* gB0 = Bp + ((size_t)e * NTOT + n0 + ob0) * K + (tcol >> 1);
    const _Float16* gB1 = (LPB == 2) ? Bp + ((size_t)e * NTOT + n0 + ob1) * K + (tcol >> 1)
                                     : gB0;

    floatx4 acc[2 * MH][4] = {};
    f16x8 af[MH][2], bf[2][2];

    // prologue: kt0 full + kt1 minus B.h0 (staged at iter0 ph1)
    STA(0, 0, 0); STA(0, 0, 1); STB(0, 0, 0); STB(0, 0, 1);
    STA(1, 64, 0); STB(1, 64, 1); STA(1, 64, 1);
    VMC0(); BAR();

#pragma unroll 1
    for (int i = 0; i < NI - 1; ++i) {
        ITER(1);
        gA0 += 128; gA1 += 128; gB0 += 128; gB1 += 128;
    }
    ITER(0);

    if constexpr (EPI1) {
        // bias + gelu + fp16 repack + 16B coalesced H1 stores
        const float* be = bias + (size_t)e * NTOT + n0 + wn * 64;
        float bb[4];
#pragma unroll
        for (int ni = 0; ni < 4; ++ni) bb[ni] = be[ni * 16 + lm];
        _Float16* wbuf = smem + wv * (16 * 72);
        int rowg0 = row0 + wm * WM;
        int colg0 = n0 + wn * 64;
#pragma unroll
        for (int mi = 0; mi < 2 * MH; ++mi) {
#pragma unroll
            for (int ni = 0; ni < 4; ++ni)
#pragma unroll
                for (int r = 0; r < 4; ++r)
                    wbuf[(kq * 4 + r) * 72 + ni * 16 + lm] =
                        (_Float16)gelu_f(acc[mi][ni][r] + bb[ni]);
#pragma unroll
            for (int i2 = 0; i2 < 2; ++i2) {
                int idx = i2 * 64 + lane;
                int rr = idx >> 3, cc = (idx & 7) * 8;
                *(f16x8*)(h1out + (size_t)(rowg0 + mi * 16 + rr) * NTOT + colg0 + cc) =
                    *(const f16x8*)(wbuf + rr * 72 + cc);
            }
        }
    } else {
        int end = off[e] + counts[e];
#pragma unroll
        for (int mi = 0; mi < 2 * MH; ++mi) {
            int rbase = row0 + wm * WM + mi * 16 + kq * 4;
#pragma unroll
            for (int r = 0; r < 4; ++r) {
                int s = rbase + r;
                if (s >= end) continue;        // pad rows never read
#pragma unroll
                for (int ni = 0; ni < 4; ++ni) {
                    int d = n0 + wn * 64 + ni * 16 + lm;
                    yout[(size_t)s * NTOT + d] = acc[mi][ni][r];
                }
            }
        }
    }
}

#undef ITER
#undef PH_B
#undef PH_A
#undef PH_AB
#undef MMT
#undef MMG
#undef STB
#undef STA
#undef RDB
#undef RDA
#undef VMCN
#undef VMC0
#undef WLGKM
#undef SCB
#undef BAR

// ---------------- Combine: out[t] = sum_k wts[t,k] * (y[slot_k] + b2[e_k]) ----------------
__global__ __launch_bounds__(256) void combine_kernel(
    const float* __restrict__ y, const int* __restrict__ slot_of,
    const float* __restrict__ wts, const int* __restrict__ sel,
    const float* __restrict__ b2, float* __restrict__ out)
{
    int t = blockIdx.x, i = threadIdx.x;
    int s0 = slot_of[2*t], s1 = slot_of[2*t+1];
    int e0 = sel[2*t], e1 = sel[2*t+1];
    float w0 = wts[2*t], w1 = wts[2*t+1];
    float4 y0 = ((const float4*)(y + (size_t)s0 * DIM))[i];
    float4 y1 = ((const float4*)(y + (size_t)s1 * DIM))[i];
    float4 c0 = ((const float4*)(b2 + (size_t)e0 * DIM))[i];
    float4 c1 = ((const float4*)(b2 + (size_t)e1 * DIM))[i];
    float4 o;
    o.x = w0 * (y0.x + c0.x) + w1 * (y1.x + c1.x);
    o.y = w0 * (y0.y + c0.y) + w1 * (y1.y + c1.y);
    o.z = w0 * (y0.z + c0.z) + w1 * (y1.z + c1.z);
    o.w = w0 * (y0.w + c0.w) + w1 * (y1.w + c1.w);
    ((float4*)(out + (size_t)t * DIM))[i] = o;
}

extern "C" void kernel_launch(void* const* d_in, const int* in_sizes, int n_in,
                              void* d_out, int out_size, void* d_ws, size_t ws_size,
                              hipStream_t stream)
{
    const float* x    = (const float*)d_in[0];
    const float* gw   = (const float*)d_in[1];
    const float* ln_s = (const float*)d_in[2];
    const float* ln_b = (const float*)d_in[3];
    const float* w1   = (const float*)d_in[4];
    const float* b1   = (const float*)d_in[5];
    const float* w2   = (const float*)d_in[6];
    const float* b2   = (const float*)d_in[7];
    float* out = (float*)d_out;

    char* p = (char*)d_ws;
    auto carve = [&](size_t bytes) -> char* {
        char* r = p;
        p += (bytes + 255) & ~(size_t)255;
        return r;
    };
    int*   counts    = (int*)carve(NE * 4);
    int*   off       = (int*)carve((NE + 1) * 4);
    int*   tile_exp  = (int*)carve(NT256 * 4);
    int*   blockhist = (int*)carve(32 * NE * 4);
    int*   babs      = (int*)carve(32 * NE * 4);
    int*   sel       = (int*)carve((size_t)T_TOK * 2 * 4);
    float* wts       = (float*)carve((size_t)T_TOK * 2 * 4);
    float* mu_arr    = (float*)carve((size_t)T_TOK * 4);
    float* rstd_arr  = (float*)carve((size_t)T_TOK * 4);
    int*   slot_of   = (int*)carve((size_t)T_TOK * 2 * 4);
    unsigned short* lrank = (unsigned short*)carve((size_t)T_TOK * 2 * 2);
    _Float16* xg  = (_Float16*)carve((size_t)CAP_ROWS * DIM * 2);  // 37.7 MB
    _Float16* w1t = (_Float16*)carve((size_t)NE * DIM * HID * 2);  // 67.1 MB
    _Float16* w2t = (_Float16*)carve((size_t)NE * DIM * HID * 2);
    _Float16* H1  = (_Float16*)carve((size_t)CAP_ROWS * HID * 2);  // 151 MB
    // y (75.5 MB fp32) aliases xg+w1t (104.8 MB) — both dead after gemm1
    float* y = (float*)xg;

    gating_ln_kernel<<<T_TOK, 256, 0, stream>>>(x, gw, sel, wts, mu_arr, rstd_arr);
    hist_kernel<<<32, 256, 0, stream>>>(sel, blockhist, lrank);
    scan_kernel<<<1, 256, 0, stream>>>(blockhist, off, counts, babs, tile_exp);
    scatter_kernel<<<T_TOK, 256, 0, stream>>>(x, ln_s, ln_b, sel, mu_arr, rstd_arr,
                                              babs, lrank, xg, slot_of);
    transpose_cvt_kernel<<<dim3(HID/64, DIM/64, NE), 256, 0, stream>>>(w1, w1t, DIM, HID);
    transpose_cvt_kernel<<<dim3(DIM/64, HID/64, NE), 256, 0, stream>>>(w2, w2t, HID, DIM);

    // GEMM1: H1 = gelu(xg @ w1 + b1)   [256x256 tiles, K=1024]
    gemm8p_kernel<256, HID, DIM, true><<<NT256 * (HID / 256), 512, 0, stream>>>(
        xg, w1t, b1, tile_exp, off, counts, H1, nullptr);
    // GEMM2: y = H1 @ w2               [256x128 tiles, K=4096]
    gemm8p_kernel<128, DIM, HID, false><<<NT256 * (DIM / 128), 512, 0, stream>>>(
        H1, w2t, nullptr, tile_exp, off, counts, nullptr, y);

    combine_kernel<<<T_TOK, 256, 0, stream>>>(y, slot_of, wts, sel, b2, out);
}

// Round 5
// 787.487 us; speedup vs baseline: 1.4744x; 1.0100x over previous
//
#include <hip/hip_runtime.h>
#include <hip/hip_bf16.h>
#include <hip/hip_fp16.h>
#include <math.h>

#define T_TOK 8192
#define DIM   1024
#define HID   4096
#define NE    8
#define NT256 72                    // max 256-row slabs: 16384 + 8*255 <= 72*256
#define CAP_ROWS (NT256 * 256)      // 18432 padded slots

typedef _Float16 f16x8 __attribute__((ext_vector_type(8)));
typedef float    floatx4 __attribute__((ext_vector_type(4)));

__device__ __forceinline__ void gload_lds16(const void* g, void* l) {
    __builtin_amdgcn_global_load_lds(
        (const __attribute__((address_space(1))) void*)g,
        (__attribute__((address_space(3))) void*)l,
        16, 0, 0);
}

// tanh-form GELU (max dev from exact ~1e-3)
__device__ __forceinline__ float gelu_f(float v) {
    float u = v * (0.7978845608028654f + 0.03567740813636141f * v * v);
    float e = exp2f(2.8853900817779268f * u);     // exp(2u)
    float th = 1.f - 2.f / (e + 1.f);
    return 0.5f * v * (1.f + th);
}

// ---------------- Pass 1a: gating + LN stats (no atomics) ----------------
__global__ __launch_bounds__(256) void gating_ln_kernel(
    const float* __restrict__ x, const float* __restrict__ gw,
    int* __restrict__ sel, float* __restrict__ wts,
    float* __restrict__ mu_arr, float* __restrict__ rstd_arr)
{
    int t = blockIdx.x;
    int tid = threadIdx.x;
    float4 xv = ((const float4*)(x + (size_t)t * DIM))[tid];
    float s  = xv.x + xv.y + xv.z + xv.w;
    float ss = xv.x*xv.x + xv.y*xv.y + xv.z*xv.z + xv.w*xv.w;
    float l[NE];
#pragma unroll
    for (int e = 0; e < NE; e++) l[e] = 0.f;
    int d0 = tid * 4;
    const float* xp = &xv.x;
#pragma unroll
    for (int j = 0; j < 4; j++) {
        float xj = xp[j];
        const float4* g = (const float4*)(gw + (size_t)(d0 + j) * NE);
        float4 g0 = g[0], g1 = g[1];
        l[0] += xj * g0.x; l[1] += xj * g0.y; l[2] += xj * g0.z; l[3] += xj * g0.w;
        l[4] += xj * g1.x; l[5] += xj * g1.y; l[6] += xj * g1.z; l[7] += xj * g1.w;
    }
#pragma unroll
    for (int off = 32; off > 0; off >>= 1) {
        s  += __shfl_down(s, off);
        ss += __shfl_down(ss, off);
#pragma unroll
        for (int e = 0; e < NE; e++) l[e] += __shfl_down(l[e], off);
    }
    __shared__ float red[4][10];
    int lane = tid & 63, wv = tid >> 6;
    if (lane == 0) {
        red[wv][0] = s; red[wv][1] = ss;
        for (int e = 0; e < NE; e++) red[wv][2 + e] = l[e];
    }
    __syncthreads();
    if (tid == 0) {
        float S = 0.f, SS = 0.f, L[NE];
        for (int e = 0; e < NE; e++) L[e] = 0.f;
        for (int w = 0; w < 4; w++) {
            S += red[w][0]; SS += red[w][1];
            for (int e = 0; e < NE; e++) L[e] += red[w][2 + e];
        }
        float mu  = S * (1.f / DIM);
        float var = SS * (1.f / DIM) - mu * mu;
        float rstd = rsqrtf(var + 1e-5f);
        float lmax = L[0];
        for (int e = 1; e < NE; e++) lmax = fmaxf(lmax, L[e]);
        float den = 0.f;
        for (int e = 0; e < NE; e++) den += expf(L[e] - lmax);
        int i0 = 0; float b0 = L[0];
        for (int e = 1; e < NE; e++) if (L[e] > b0) { b0 = L[e]; i0 = e; }
        int i1 = -1; float b1v = -3.4e38f;
        for (int e = 0; e < NE; e++) if (e != i0 && L[e] > b1v) { b1v = L[e]; i1 = e; }
        float p0 = expf(b0 - lmax) / den;
        float p1 = expf(b1v - lmax) / den;
        float t1 = expf(p1 - p0);            // p1 <= p0, stable
        float w0 = 1.f / (1.f + t1);
        float w1 = t1 / (1.f + t1);
        sel[2*t] = i0;  sel[2*t+1] = i1;
        wts[2*t] = w0;  wts[2*t+1] = w1;
        mu_arr[t] = mu; rstd_arr[t] = rstd;
    }
}

// ---------------- Pass 1b-i: per-block histogram + local ranks (atomic-free) ----------------
__global__ __launch_bounds__(256) void hist_kernel(
    const int* __restrict__ sel, int* __restrict__ blockhist,
    unsigned short* __restrict__ lrank)
{
    int b = blockIdx.x, tid = threadIdx.x;
    int t = b * 256 + tid;
    int e0 = sel[2*t], e1 = sel[2*t+1];
    int lane = tid & 63, w = tid >> 6;
    __shared__ int c0[4][NE], c1[4][NE];
    unsigned long long below = (1ull << lane) - 1ull;
    int r0 = 0, r1 = 0;
#pragma unroll
    for (int e = 0; e < NE; e++) {
        unsigned long long m0 = __ballot(e0 == e);
        unsigned long long m1 = __ballot(e1 == e);
        if (lane == 0) { c0[w][e] = __popcll(m0); c1[w][e] = __popcll(m1); }
        if (e0 == e) r0 = __popcll(m0 & below);
        if (e1 == e) r1 = __popcll(m1 & below);
    }
    __syncthreads();
    int base0 = 0, base1 = 0;
#pragma unroll
    for (int wp = 0; wp < 4; wp++) {
        if (wp < w) { base0 += c0[wp][e0]; base1 += c1[wp][e1]; }
        base1 += c0[wp][e1];          // e1-stream ranks after all e0-stream picks
    }
    lrank[2*t]   = (unsigned short)(base0 + r0);
    lrank[2*t+1] = (unsigned short)(base1 + r1);
    if (tid < NE) {
        int sum = 0;
        for (int wp = 0; wp < 4; wp++) sum += c0[wp][tid] + c1[wp][tid];
        blockhist[b * NE + tid] = sum;
    }
}

// ---------------- Pass 1b-ii: scan blocks, 256-aligned offsets, tile map ----------------
__global__ __launch_bounds__(256) void scan_kernel(
    const int* __restrict__ blockhist, int* __restrict__ off, int* __restrict__ counts,
    int* __restrict__ babs, int* __restrict__ tile_expert)
{
    __shared__ int soff[NE + 1];
    __shared__ int stot[NE];
    int tid = threadIdx.x;
    if (tid < NE) {
        int tot = 0;
        for (int b = 0; b < 32; b++) tot += blockhist[b * NE + tid];
        stot[tid] = tot; counts[tid] = tot;
    }
    __syncthreads();
    if (tid == 0) {
        int o = 0;
        for (int e = 0; e < NE; e++) { soff[e] = o; off[e] = o; o += ((stot[e] + 255) >> 8) << 8; }
        soff[NE] = o; off[NE] = o;
    }
    __syncthreads();
    if (tid < NE) {
        int run = soff[tid];
        for (int b = 0; b < 32; b++) { babs[b * NE + tid] = run; run += blockhist[b * NE + tid]; }
    }
    int o = soff[NE];
    for (int i = tid; i < NT256; i += 256) {
        int pos = i * 256, e = -1;
        if (pos < o) {
            for (int j = 0; j < NE; j++)
                if (pos >= soff[j] && pos < soff[j + 1]) { e = j; break; }
        }
        tile_expert[i] = e;
    }
}

// ---------------- Pass 1c: scatter normalized tokens (atomic-free) ----------------
__global__ __launch_bounds__(256) void scatter_kernel(
    const float* __restrict__ x, const float* __restrict__ ln_s, const float* __restrict__ ln_b,
    const int* __restrict__ sel,
    const float* __restrict__ mu_arr, const float* __restrict__ rstd_arr,
    const int* __restrict__ babs, const unsigned short* __restrict__ lrank,
    _Float16* __restrict__ xg, int* __restrict__ slot_of)
{
    int t = blockIdx.x, tid = threadIdx.x;
    int b = t >> 8;
    int e0 = sel[2*t], e1 = sel[2*t+1];
    int s0 = babs[b * NE + e0] + (int)lrank[2*t];
    int s1 = babs[b * NE + e1] + (int)lrank[2*t+1];
    if (tid == 0) { slot_of[2*t] = s0; slot_of[2*t+1] = s1; }
    float4 xv = ((const float4*)(x + (size_t)t * DIM))[tid];
    float mu = mu_arr[t], rstd = rstd_arr[t];
    float xn0 = (xv.x - mu) * rstd, xn1 = (xv.y - mu) * rstd;
    float xn2 = (xv.z - mu) * rstd, xn3 = (xv.w - mu) * rstd;
#pragma unroll
    for (int k = 0; k < 2; k++) {
        int e = (k == 0) ? e0 : e1;
        int slot = (k == 0) ? s0 : s1;
        float4 sv = ((const float4*)(ln_s + (size_t)e * DIM))[tid];
        float4 bv = ((const float4*)(ln_b + (size_t)e * DIM))[tid];
        _Float16 hb[4];
        hb[0] = (_Float16)(xn0 * sv.x + bv.x);
        hb[1] = (_Float16)(xn1 * sv.y + bv.y);
        hb[2] = (_Float16)(xn2 * sv.z + bv.z);
        hb[3] = (_Float16)(xn3 * sv.w + bv.w);
        *(uint2*)(xg + (size_t)slot * DIM + tid * 4) = *(const uint2*)hb;
    }
}

// ---------------- Weight transpose + fp32->fp16 convert ----------------
__global__ __launch_bounds__(256) void transpose_cvt_kernel(
    const float* __restrict__ in, _Float16* __restrict__ out, int R, int C)
{
    __shared__ _Float16 tile[64][65];
    size_t ebase = (size_t)blockIdx.z * R * C;
    const float* inp = in + ebase + (size_t)(blockIdx.y * 64) * C + blockIdx.x * 64;
    _Float16* outp = out + ebase + (size_t)(blockIdx.x * 64) * R + blockIdx.y * 64;
    int t = threadIdx.x & 31, j0 = threadIdx.x >> 5;
    for (int j = j0; j < 64; j += 8) {
        float2 v = *(const float2*)(inp + (size_t)j * C + 2 * t);
        tile[j][2*t]   = (_Float16)v.x;
        tile[j][2*t+1] = (_Float16)v.y;
    }
    __syncthreads();
    for (int j = j0; j < 64; j += 8) {
        _Float16 pr[2] = { tile[2*t][j], tile[2*t+1][j] };
        *(unsigned int*)(outp + (size_t)j * R + 2 * t) = *(unsigned int*)pr;
    }
}

// ================= 8-phase 256-row-tile GEMM (T2+T3+T4+T5) =================
// r5: phase structure = r3's exact form (compiler-scheduled ds_reads + single
// lgkmcnt(0) drain per phase — measured best). New: XCD-local supertile remap
// for gemm1 (9mt x 4nt) to raise concurrent B-panel sharing 2x -> 9x.
// Bank swizzle (128B rows, b128 reads): byte ^= (row&7)<<4, applied on the
// global SOURCE col for linear-dest gload_lds and on the ds_read col.

#define BAR() __builtin_amdgcn_s_barrier()
#define WAITLGKM() asm volatile("s_waitcnt lgkmcnt(0)" ::: "memory")
#define SCB() __builtin_amdgcn_sched_barrier(0)
#define VMC0() asm volatile("s_waitcnt vmcnt(0)" ::: "memory")
#define VMCN() do { if (LPB == 2) { asm volatile("s_waitcnt vmcnt(6)" ::: "memory"); } \
                    else          { asm volatile("s_waitcnt vmcnt(5)" ::: "memory"); } } while (0)

#define DSA(B_, MHI) do {                                                        \
    const char* p_ = smb + (B_) * (2 * BUFH) + (MHI) * 16384 + aob;              \
    _Pragma("unroll")                                                            \
    for (int mi_ = 0; mi_ < MH; ++mi_) {                                         \
        af[mi_][0] = *(const f16x8*)(p_ + mi_ * 2048 + kx0);                     \
        af[mi_][1] = *(const f16x8*)(p_ + mi_ * 2048 + kx1);                     \
    }                                                                            \
} while (0)

#define DSB(B_, NHI) do {                                                        \
    const char* p_ = smb + (B_) * (2 * BUFH) + (NHI) * (BN * 64) + bob;          \
    _Pragma("unroll")                                                            \
    for (int tn_ = 0; tn_ < 2; ++tn_) {                                          \
        bf[tn_][0] = *(const f16x8*)(p_ + tn_ * 2048 + kx0);                     \
        bf[tn_][1] = *(const f16x8*)(p_ + tn_ * 2048 + kx1);                     \
    }                                                                            \
} while (0)

#define STA(B_, KOFF, H_) do {                                                   \
    _Float16* d_ = smem + (B_) * BUFH + (H_) * 8192 + tid * 8;                   \
    gload_lds16(gA0 + (size_t)((H_) * (WM / 2)) * K + (KOFF), d_);               \
    gload_lds16(gA1 + (size_t)((H_) * (WM / 2)) * K + (KOFF), d_ + 4096);        \
} while (0)

#define STB(B_, KOFF, H_) do {                                                   \
    _Float16* d_ = smem + (B_) * BUFH + 16384 + (H_) * BHH + tid * 8;            \
    gload_lds16(gB0 + (size_t)((H_) * 32) * K + (KOFF), d_);                     \
    if (LPB == 2) gload_lds16(gB1 + (size_t)((H_) * 32) * K + (KOFF), d_ + 4096);\
} while (0)

#define MM(MHI, NHI) do {                                                        \
    _Pragma("unroll")                                                            \
    for (int mi_ = 0; mi_ < MH; ++mi_) {                                         \
        _Pragma("unroll")                                                        \
        for (int tn_ = 0; tn_ < 2; ++tn_) {                                      \
            floatx4* a_ = &acc[(MHI) * MH + mi_][(NHI) * 2 + tn_];               \
            *a_ = __builtin_amdgcn_mfma_f32_16x16x32_f16(af[mi_][0], bf[tn_][0], *a_, 0, 0, 0); \
            *a_ = __builtin_amdgcn_mfma_f32_16x16x32_f16(af[mi_][1], bf[tn_][1], *a_, 0, 0, 0); \
        }                                                                        \
    }                                                                            \
} while (0)

#define PH_MM(MHI, NHI)                                                          \
    BAR(); WAITLGKM(); SCB();                                                    \
    __builtin_amdgcn_s_setprio(1); MM(MHI, NHI); __builtin_amdgcn_s_setprio(0);

// stage schedule (iter i, K-tiles 2i/2i+1 live, staging 2i+2/2i+3):
// ph1:B1h0(kt2i+1) ph2:A0h0 ph3:B0h1 ph4:A0h1 [vmcnt] ph5:B0h0 ph6:A1h0 ph7:B1h1 ph8:A1h1 [vmcnt]
#define ITER(SON) do {                                                           \
    DSA(0, 0); DSB(0, 0); STB(1, 64, 0);                                         \
    PH_MM(0, 0) BAR();                                                           \
    DSB(0, 1); if (SON) STA(0, 128, 0);                                          \
    PH_MM(0, 1) BAR();                                                           \
    DSA(0, 1); if (SON) STB(0, 128, 1);                                          \
    PH_MM(1, 1) BAR();                                                           \
    DSB(0, 0); if (SON) STA(0, 128, 1);                                          \
    PH_MM(1, 0) if (SON) { VMCN(); } else { VMC0(); } BAR();                     \
    DSA(1, 0); DSB(1, 0); if (SON) STB(0, 128, 0);                               \
    PH_MM(0, 0) BAR();                                                           \
    DSB(1, 1); if (SON) STA(1, 192, 0);                                          \
    PH_MM(0, 1) BAR();                                                           \
    DSA(1, 1); if (SON) STB(1, 192, 1);                                          \
    PH_MM(1, 1) BAR();                                                           \
    DSB(1, 0); if (SON) STA(1, 192, 1);                                          \
    PH_MM(1, 0) if (SON) { VMCN(); } BAR();                                      \
} while (0)

template <int BN, int NTOT, int K, bool EPI1>
__global__ __launch_bounds__(512, 2) void gemm8p_kernel(
    const _Float16* __restrict__ Ap,
    const _Float16* __restrict__ Bp,
    const float* __restrict__ bias,
    const int* __restrict__ tile_expert,
    const int* __restrict__ off, const int* __restrict__ counts,
    _Float16* __restrict__ h1out, float* __restrict__ yout)
{
    constexpr int WARPS_N = BN / 64;          // 4 or 2
    constexpr int WM = 256 / (8 / WARPS_N);   // 128 or 64 rows per wave
    constexpr int MH = WM / 32;               // m-tiles per half-quadrant: 4 or 2
    constexpr int LPB = BN / 128;             // gloads per B half: 2 or 1
    constexpr int BHH = BN * 32;              // halves per B half region
    constexpr int BUFH = 16384 + BN * 64;     // halves per buffer
    constexpr int NT_N = NTOT / BN;
    constexpr int NI = K / 128;               // main iters (2 K-tiles each)

    __shared__ _Float16 smem[2 * BUFH];
    const char* smb = (const char*)smem;

    int bid = blockIdx.x;
    constexpr int CHUNK = (NT256 * NT_N) / 8; // per-XCD slots (grid % 8 == 0)
    int xcd = bid & 7, slot = bid >> 3;       // slot in [0, CHUNK)
    int mt, nt;
    if constexpr (NT_N == 16) {
        // 9mt x 4nt supertiles: concurrent 32 blocks share B-panels 9-way.
        int sg = slot / 36, w = slot % 36;    // 144 = 4 x 36, bijective
        mt = xcd * 9 + (w % 9);
        nt = sg * 4 + (w / 9);
    } else {
        mt = xcd * (CHUNK / NT_N) + slot / NT_N;
        nt = slot % NT_N;
    }
    int e = tile_expert[mt];
    if (e < 0) return;
    int row0 = mt * 256, n0 = nt * BN;

    int tid = threadIdx.x;
    int lane = tid & 63, wv = tid >> 6;
    int wn = wv % WARPS_N, wm = wv / WARPS_N;
    int lm = lane & 15, kq = lane >> 4;
    int kx0 = (kq * 16) ^ ((lm & 7) << 4);                 // read-side swizzle (bytes)
    int kx1 = kx0 ^ 64;                                    // second k-fragment
    int aob = (wm * (WM / 2) + lm) * 128;                  // A lds row base (bytes)
    int bob = 32768 + (wn * 32 + lm) * 128;                // B lds row base (bytes)

    // staging: dest row j = r*64 + trow (linear); source row = interleave(j)
    int trow = tid >> 3;
    int tcol = ((tid & 7) * 16) ^ ((trow & 7) << 4);       // source-side swizzle
    int j1 = trow + 64;
    int oa0 = (trow / (WM / 2)) * WM + (trow % (WM / 2));
    int oa1 = (j1 / (WM / 2)) * WM + (j1 % (WM / 2));
    int ob0 = (trow >> 5) * 64 + (trow & 31);
    int ob1 = (j1 >> 5) * 64 + (j1 & 31);
    const _Float16* gA0 = Ap + ((size_t)(row0 + oa0)) * K + (tcol >> 1);
    const _Float16* gA1 = Ap + ((size_t)(row0 + oa1)) * K + (tcol >> 1);
    const _Float16* gB0 = Bp + ((size_t)e * NTOT + n0 + ob0) * K + (tcol >> 1);
    const _Float16* gB1 = (LPB == 2) ? Bp + ((size_t)e * NTOT + n0 + ob1) * K + (tcol >> 1)
                                     : gB0;

    floatx4 acc[2 * MH][4] = {};
    f16x8 af[MH][2], bf[2][2];

    // prologue: kt0 full + kt1 minus B.h0 (staged at iter0 ph1)
    STA(0, 0, 0); STA(0, 0, 1); STB(0, 0, 0); STB(0, 0, 1);
    STA(1, 64, 0); STB(1, 64, 1); STA(1, 64, 1);
    VMC0(); BAR();

#pragma unroll 1
    for (int i = 0; i < NI - 1; ++i) {
        ITER(1);
        gA0 += 128; gA1 += 128; gB0 += 128; gB1 += 128;
    }
    ITER(0);

    if constexpr (EPI1) {
        // bias + gelu + fp16 repack + 16B coalesced H1 stores
        const float* be = bias + (size_t)e * NTOT + n0 + wn * 64;
        float bb[4];
#pragma unroll
        for (int ni = 0; ni < 4; ++ni) bb[ni] = be[ni * 16 + lm];
        _Float16* wbuf = smem + wv * (16 * 72);
        int rowg0 = row0 + wm * WM;
        int colg0 = n0 + wn * 64;
#pragma unroll
        for (int mi = 0; mi < 2 * MH; ++mi) {
#pragma unroll
            for (int ni = 0; ni < 4; ++ni)
#pragma unroll
                for (int r = 0; r < 4; ++r)
                    wbuf[(kq * 4 + r) * 72 + ni * 16 + lm] =
                        (_Float16)gelu_f(acc[mi][ni][r] + bb[ni]);
#pragma unroll
            for (int i2 = 0; i2 < 2; ++i2) {
                int idx = i2 * 64 + lane;
                int rr = idx >> 3, cc = (idx & 7) * 8;
                *(f16x8*)(h1out + (size_t)(rowg0 + mi * 16 + rr) * NTOT + colg0 + cc) =
                    *(const f16x8*)(wbuf + rr * 72 + cc);
            }
        }
    } else {
        int end = off[e] + counts[e];
#pragma unroll
        for (int mi = 0; mi < 2 * MH; ++mi) {
            int rbase = row0 + wm * WM + mi * 16 + kq * 4;
#pragma unroll
            for (int r = 0; r < 4; ++r) {
                int s = rbase + r;
                if (s >= end) continue;        // pad rows never read
#pragma unroll
                for (int ni = 0; ni < 4; ++ni) {
                    int d = n0 + wn * 64 + ni * 16 + lm;
                    yout[(size_t)s * NTOT + d] = acc[mi][ni][r];
                }
            }
        }
    }
}

#undef ITER
#undef PH_MM
#undef MM
#undef STB
#undef STA
#undef DSB
#undef DSA
#undef VMCN
#undef VMC0
#undef SCB
#undef WAITLGKM
#undef BAR

// ---------------- Combine: out[t] = sum_k wts[t,k] * (y[slot_k] + b2[e_k]) ----------------
__global__ __launch_bounds__(256) void combine_kernel(
    const float* __restrict__ y, const int* __restrict__ slot_of,
    const float* __restrict__ wts, const int* __restrict__ sel,
    const float* __restrict__ b2, float* __restrict__ out)
{
    int t = blockIdx.x, i = threadIdx.x;
    int s0 = slot_of[2*t], s1 = slot_of[2*t+1];
    int e0 = sel[2*t], e1 = sel[2*t+1];
    float w0 = wts[2*t], w1 = wts[2*t+1];
    float4 y0 = ((const float4*)(y + (size_t)s0 * DIM))[i];
    float4 y1 = ((const float4*)(y + (size_t)s1 * DIM))[i];
    float4 c0 = ((const float4*)(b2 + (size_t)e0 * DIM))[i];
    float4 c1 = ((const float4*)(b2 + (size_t)e1 * DIM))[i];
    float4 o;
    o.x = w0 * (y0.x + c0.x) + w1 * (y1.x + c1.x);
    o.y = w0 * (y0.y + c0.y) + w1 * (y1.y + c1.y);
    o.z = w0 * (y0.z + c0.z) + w1 * (y1.z + c1.z);
    o.w = w0 * (y0.w + c0.w) + w1 * (y1.w + c1.w);
    ((float4*)(out + (size_t)t * DIM))[i] = o;
}

extern "C" void kernel_launch(void* const* d_in, const int* in_sizes, int n_in,
                              void* d_out, int out_size, void* d_ws, size_t ws_size,
                              hipStream_t stream)
{
    const float* x    = (const float*)d_in[0];
    const float* gw   = (const float*)d_in[1];
    const float* ln_s = (const float*)d_in[2];
    const float* ln_b = (const float*)d_in[3];
    const float* w1   = (const float*)d_in[4];
    const float* b1   = (const float*)d_in[5];
    const float* w2   = (const float*)d_in[6];
    const float* b2   = (const float*)d_in[7];
    float* out = (float*)d_out;

    char* p = (char*)d_ws;
    auto carve = [&](size_t bytes) -> char* {
        char* r = p;
        p += (bytes + 255) & ~(size_t)255;
        return r;
    };
    int*   counts    = (int*)carve(NE * 4);
    int*   off       = (int*)carve((NE + 1) * 4);
    int*   tile_exp  = (int*)carve(NT256 * 4);
    int*   blockhist = (int*)carve(32 * NE * 4);
    int*   babs      = (int*)carve(32 * NE * 4);
    int*   sel       = (int*)carve((size_t)T_TOK * 2 * 4);
    float* wts       = (float*)carve((size_t)T_TOK * 2 * 4);
    float* mu_arr    = (float*)carve((size_t)T_TOK * 4);
    float* rstd_arr  = (float*)carve((size_t)T_TOK * 4);
    int*   slot_of   = (int*)carve((size_t)T_TOK * 2 * 4);
    unsigned short* lrank = (unsigned short*)carve((size_t)T_TOK * 2 * 2);
    _Float16* xg  = (_Float16*)carve((size_t)CAP_ROWS * DIM * 2);  // 37.7 MB
    _Float16* w1t = (_Float16*)carve((size_t)NE * DIM * HID * 2);  // 67.1 MB
    _Float16* w2t = (_Float16*)carve((size_t)NE * DIM * HID * 2);
    _Float16* H1  = (_Float16*)carve((size_t)CAP_ROWS * HID * 2);  // 151 MB
    // y (75.5 MB fp32) aliases xg+w1t (104.8 MB) — both dead after gemm1
    float* y = (float*)xg;

    gating_ln_kernel<<<T_TOK, 256, 0, stream>>>(x, gw, sel, wts, mu_arr, rstd_arr);
    hist_kernel<<<32, 256, 0, stream>>>(sel, blockhist, lrank);
    scan_kernel<<<1, 256, 0, stream>>>(blockhist, off, counts, babs, tile_exp);
    scatter_kernel<<<T_TOK, 256, 0, stream>>>(x, ln_s, ln_b, sel, mu_arr, rstd_arr,
                                              babs, lrank, xg, slot_of);
    transpose_cvt_kernel<<<dim3(HID/64, DIM/64, NE), 256, 0, stream>>>(w1, w1t, DIM, HID);
    transpose_cvt_kernel<<<dim3(DIM/64, HID/64, NE), 256, 0, stream>>>(w2, w2t, HID, DIM);

    // GEMM1: H1 = gelu(xg @ w1 + b1)   [256x256 tiles, K=1024]
    gemm8p_kernel<256, HID, DIM, true><<<NT256 * (HID / 256), 512, 0, stream>>>(
        xg, w1t, b1, tile_exp, off, counts, H1, nullptr);
    // GEMM2: y = H1 @ w2               [256x128 tiles, K=4096]
    gemm8p_kernel<128, DIM, HID, false><<<NT256 * (DIM / 128), 512, 0, stream>>>(
        H1, w2t, nullptr, tile_exp, off, counts, nullptr, y);

    combine_kernel<<<T_TOK, 256, 0, stream>>>(y, slot_of, wts, sel, b2, out);
}